// Round 16
// baseline (601.222 us; speedup 1.0000x reference)
//
#include <hip/hip_runtime.h>
#include <math.h>

#define C_ 32
#define H_ 256
#define W_ 256
#define HW_ 65536
#define CHW_ 2097152          // one image's activation, elements
#define TWO_PI 6.28318530717958647692f

typedef __bf16 bf16x8 __attribute__((ext_vector_type(8)));
typedef float  f32x4  __attribute__((ext_vector_type(4)));

__device__ __forceinline__ bf16x8 as_bf16x8(uint4 u) {
    return __builtin_bit_cast(bf16x8, u);
}
__device__ __forceinline__ unsigned short bfbits(__bf16 h) {
    return __builtin_bit_cast(unsigned short, h);
}
__device__ __forceinline__ __bf16 bfval(unsigned short u) {
    return __builtin_bit_cast(__bf16, u);
}
__device__ __forceinline__ bf16x8 mk8(unsigned a, unsigned b, unsigned c, unsigned d) {
    return __builtin_bit_cast(bf16x8, make_uint4(a, b, c, d));
}
__device__ __forceinline__ unsigned rot16(unsigned v) { return (v >> 16) | (v << 16); }
// Split (x,y) into bf16 hi/lo packs: .x = xh|yh<<16, .y = xl|yl<<16.
__device__ __forceinline__ uint2 splitpack(float x, float y) {
    __bf16 xh = (__bf16)x, yh = (__bf16)y;
    float xl = x - (float)xh, yl = y - (float)yh;
    unsigned hi = (unsigned)bfbits(xh) | ((unsigned)bfbits(yh) << 16);
    unsigned lo = (unsigned)bfbits((__bf16)xl) | ((unsigned)bfbits((__bf16)yl) << 16);
    return make_uint2(hi, lo);
}

__device__ __forceinline__ float gelu_exact(float x) {
    return 0.5f * x * (1.0f + erff(x * 0.7071067811865475f));
}

__global__ void k_probe(float* __restrict__ out, float ws_kib) {
    if (threadIdx.x == 0 && blockIdx.x == 0) out[0] = ws_kib;
}

// ---------------------------------------------------------------------------
// K0 (r26): one-shot twiddle-table prep (fixed offsets, verified r26).
// ---------------------------------------------------------------------------
__global__ __launch_bounds__(256)
void k_twprep(unsigned short* __restrict__ twfg, uint2* __restrict__ twbfg,
              float2* __restrict__ twg) {
    int f = blockIdx.x * 256 + threadIdx.x;  // grid 32 -> 0..8191
    {
        int i  = f & 7;
        int c  = (f >> 3) & 15;              // kx
        int g  = (f >> 7) & 3;
        int nt = (f >> 9) & 1;               // 0: re (cos), 1: im (-sin)
        int kk = f >> 10;
        int k  = kk * 32 + 8 * g + i;        // w index
        int a  = (k * c) & 255;
        float ang = (float)a * (TWO_PI / 256.0f);
        float s_, c_; sincosf(ang, &s_, &c_);
        float val = nt ? -s_ : c_;
        __bf16 hi = (__bf16)val;
        __bf16 lo = (__bf16)(val - (float)hi);
        twfg[f]        = bfbits(hi);
        twfg[8192 + f] = bfbits(lo);
    }
    if (f < 256) {
        float a = TWO_PI * (1.0f / 256.0f) * (float)f;
        float s_, c_; sincosf(a, &s_, &c_);
        twbfg[f] = splitpack(c_, s_);
        twg[f]   = make_float2(c_, s_);
    }
}

// ---------------------------------------------------------------------------
// K1 (r27): lift -> split-bf16 activation (hi plane [0,ae), lo plane [ae,2ae)).
// Stored (hi,lo) = exactly what consumers previously computed from f32.
// ---------------------------------------------------------------------------
__global__ __launch_bounds__(256)
void k_lift(const float* __restrict__ xb, const float* __restrict__ fc0_w,
            const float* __restrict__ fc0_b, unsigned short* __restrict__ out,
            int ae) {
    __shared__ float wsh[12 * 32];
    __shared__ float bsh[32];
    int tid = threadIdx.x;
    for (int n = tid; n < 384; n += 256) wsh[n] = fc0_w[n];
    if (tid < 32) bsh[tid] = fc0_b[tid];
    __syncthreads();
    int p = blockIdx.x * 256 + tid;          // b<<16 | h<<8 | w
    int w = p & 255;
    int h = (p >> 8) & 255;
    float in[12];
    const float* xp = xb + (size_t)p * 10;
    #pragma unroll
    for (int t = 0; t < 10; ++t) in[t] = xp[t];
    in[10] = (float)h * (1.0f / 255.0f);
    in[11] = (float)w * (1.0f / 255.0f);
    size_t base = (size_t)(p & 0xFFFF) + (size_t)(p >> 16) * CHW_;
    unsigned short* oh = out + base;
    unsigned short* ol = out + (size_t)ae + base;
    #pragma unroll
    for (int c = 0; c < 32; ++c) {
        float acc = bsh[c];
        #pragma unroll
        for (int t = 0; t < 12; ++t) acc += in[t] * wsh[t * 32 + c];
        __bf16 hb = (__bf16)acc;
        oh[(size_t)c * HW_] = bfbits(hb);
        ol[(size_t)c * HW_] = bfbits((__bf16)(acc - (float)hb));
    }
}

// ---------------------------------------------------------------------------
// K2 (r27): FUSED forward W-DFT + H-DFT. X now split-bf16: A fragments are
// direct uint4 loads from the hi/lo planes — ZERO repack VALU (was 512/wave-
// tile). Fragment bits identical to r26. Phase B unchanged.
// ---------------------------------------------------------------------------
__global__ __launch_bounds__(512)
void k_dftw_dfth(const unsigned short* __restrict__ X, int ae,
                 float* __restrict__ G,
                 const unsigned short* __restrict__ twfg,
                 const uint2* __restrict__ twbfg) {
    __shared__ __align__(16) unsigned short twf[16384];   // [hi/lo][kk][nt][g][c][i]
    __shared__ uint2 twbf[256];
    __shared__ uint2 slp[256][17];                        // (re_h|im_h, re_l|im_l), +1 pad
    int tid = threadIdx.x;
    {
        const uint4* tf4 = (const uint4*)twfg;
        uint4* tw4 = (uint4*)twf;
        #pragma unroll
        for (int f = tid; f < 2048; f += 512) tw4[f] = tf4[f];
        if (tid < 256) twbf[tid] = twbfg[tid];
    }
    __syncthreads();
    int wv = tid >> 6, lane = tid & 63, kg = lane >> 4, cl = lane & 15;
    const uint4* twp = (const uint4*)twf;    // 2048 fragments of 8 bf16
    int bo = blockIdx.x;                     // b*32 + c
    const unsigned short* xh = X + (size_t)bo * HW_;
    const unsigned short* xl = X + (size_t)ae + (size_t)bo * HW_;
    // ---- phase A: W-DFT, 2 tiles (32 h-rows) per wave, slp-direct ----
    #pragma unroll
    for (int tt = 0; tt < 2; ++tt) {
        int t = wv * 2 + tt;                 // tile: rows h = t*16 .. t*16+15
        size_t rowb = (size_t)(t * 16 + cl) * 256 + 8 * kg;
        f32x4 acc0 = {0.f, 0.f, 0.f, 0.f};   // re[kx=cl]
        f32x4 acc1 = {0.f, 0.f, 0.f, 0.f};   // im[kx=cl]
        #pragma unroll
        for (int kk = 0; kk < 8; ++kk) {
            bf16x8 Ah = as_bf16x8(*(const uint4*)(xh + rowb + kk * 32));
            bf16x8 Al = as_bf16x8(*(const uint4*)(xl + rowb + kk * 32));
            int base = kk * 128 + kg * 16 + cl;          // uint4 index, hi, nt=0
            bf16x8 Bh0 = as_bf16x8(twp[base]);
            bf16x8 Bh1 = as_bf16x8(twp[base + 64]);
            bf16x8 Bl0 = as_bf16x8(twp[base + 1024]);
            bf16x8 Bl1 = as_bf16x8(twp[base + 1088]);
            acc0 = __builtin_amdgcn_mfma_f32_16x16x32_bf16(Al, Bl0, acc0, 0, 0, 0);
            acc0 = __builtin_amdgcn_mfma_f32_16x16x32_bf16(Ah, Bl0, acc0, 0, 0, 0);
            acc0 = __builtin_amdgcn_mfma_f32_16x16x32_bf16(Al, Bh0, acc0, 0, 0, 0);
            acc0 = __builtin_amdgcn_mfma_f32_16x16x32_bf16(Ah, Bh0, acc0, 0, 0, 0);
            acc1 = __builtin_amdgcn_mfma_f32_16x16x32_bf16(Al, Bl1, acc1, 0, 0, 0);
            acc1 = __builtin_amdgcn_mfma_f32_16x16x32_bf16(Ah, Bl1, acc1, 0, 0, 0);
            acc1 = __builtin_amdgcn_mfma_f32_16x16x32_bf16(Al, Bh1, acc1, 0, 0, 0);
            acc1 = __builtin_amdgcn_mfma_f32_16x16x32_bf16(Ah, Bh1, acc1, 0, 0, 0);
        }
        #pragma unroll
        for (int q = 0; q < 4; ++q)
            slp[t * 16 + 4 * kg + q][cl] = splitpack(acc0[q], acc1[q]);
    }
    __syncthreads();
    // ---- phase B: H-DFT (r15 body), waves 0-3 only ----
    if (wv < 4) {
        int mt = wv >> 1, nt = wv & 1;       // m-tile, part (0=re,1=im)
        int kyi_row = mt * 16 + cl;
        int ky = (kyi_row < 16) ? kyi_row : (kyi_row + 224);
        f32x4 acc = {0.f, 0.f, 0.f, 0.f};
        #pragma unroll 4
        for (int kk = 0; kk < 16; ++kk) {
            unsigned Ah[4], Al[4], Bh[4], Bl[4];
            #pragma unroll
            for (int j2 = 0; j2 < 4; ++j2) {
                int h = kk * 16 + kg * 4 + j2;   // h index for k = kk*32+8kg+2j2
                uint2 t = twbf[(ky * h) & 255];
                Ah[j2] = t.x; Al[j2] = t.y;
                uint2 d = slp[h][cl];
                if (nt == 0) { Bh[j2] = d.x;                       Bl[j2] = d.y; }
                else         { Bh[j2] = rot16(d.x) ^ 0x80000000u;  Bl[j2] = rot16(d.y) ^ 0x80000000u; }
            }
            bf16x8 ah = mk8(Ah[0], Ah[1], Ah[2], Ah[3]);
            bf16x8 al = mk8(Al[0], Al[1], Al[2], Al[3]);
            bf16x8 bh = mk8(Bh[0], Bh[1], Bh[2], Bh[3]);
            bf16x8 bl = mk8(Bl[0], Bl[1], Bl[2], Bl[3]);
            acc = __builtin_amdgcn_mfma_f32_16x16x32_bf16(al, bl, acc, 0, 0, 0);
            acc = __builtin_amdgcn_mfma_f32_16x16x32_bf16(ah, bl, acc, 0, 0, 0);
            acc = __builtin_amdgcn_mfma_f32_16x16x32_bf16(al, bh, acc, 0, 0, 0);
            acc = __builtin_amdgcn_mfma_f32_16x16x32_bf16(ah, bh, acc, 0, 0, 0);
        }
        // D: row kyi = mt*16 + 4kg + q, col kx = cl; float idx = (f2idx)*2 + nt.
        float* gf = G + (((size_t)bo * 512 + (size_t)(mt * 16 + 4 * kg) * 16 + cl) * 2 + nt);
        #pragma unroll
        for (int q = 0; q < 4; ++q) gf[q * 32] = acc[q];
    }
}

// ---------------------------------------------------------------------------
// K5 (r26, unchanged): FUSED channel-mix + inverse H-DFT (G, T stay f32).
// ---------------------------------------------------------------------------
__global__ __launch_bounds__(256)
void k_mix_idfth(const float* __restrict__ G, const float* __restrict__ w1,
                 const float* __restrict__ w2, float* __restrict__ T,
                 const uint2* __restrict__ twbfg) {
    __shared__ uint2 twbf[256];
    __shared__ uint2 gre[32][17];
    __shared__ uint2 gim[32][17];
    int tid = threadIdx.x;
    twbf[tid] = twbfg[tid];
    int bo = blockIdx.x;                     // b*32 + o (per-image path: b=0)
    int b = bo >> 5, o = bo & 31;
    // ---- phase 1: mix (2 elements/thread) ----
    {
        int kyi = tid >> 4, kx = tid & 15;   // kyi in 0..15; elem2 = kyi+16
        const float2* gp1 = (const float2*)G + (size_t)b * 16384 + (size_t)kyi * 16 + kx;
        const float2* gp2 = gp1 + 256;       // rows kyi+16
        const float2* wv1 = (const float2*)w1 + (((size_t)o) * 16 + kyi) * 16 + kx;
        const float2* wv2 = (const float2*)w2 + (((size_t)o) * 16 + kyi) * 16 + kx;
        float ar1 = 0.f, ai1 = 0.f, ar2 = 0.f, ai2 = 0.f;
        #pragma unroll
        for (int i = 0; i < 32; ++i) {
            float2 g1 = gp1[(size_t)i * 512];
            float2 g2 = gp2[(size_t)i * 512];
            float2 wa = wv1[(size_t)i * 8192];
            float2 wb = wv2[(size_t)i * 8192];
            ar1 += g1.x * wa.x - g1.y * wa.y;
            ai1 += g1.x * wa.y + g1.y * wa.x;
            ar2 += g2.x * wb.x - g2.y * wb.y;
            ai2 += g2.x * wb.y + g2.y * wb.x;
        }
        gre[kyi][kx]      = splitpack(ar1, -ai1);
        gim[kyi][kx]      = splitpack(ai1,  ar1);
        gre[kyi + 16][kx] = splitpack(ar2, -ai2);
        gim[kyi + 16][kx] = splitpack(ai2,  ar2);
    }
    __syncthreads();
    // ---- phase 2: idfth (r15 body) ----
    int wv = tid >> 6, lane = tid & 63, kg = lane >> 4, cl = lane & 15;
    f32x4 accR[4] = {{0,0,0,0},{0,0,0,0},{0,0,0,0},{0,0,0,0}};
    f32x4 accI[4] = {{0,0,0,0},{0,0,0,0},{0,0,0,0},{0,0,0,0}};
    #pragma unroll
    for (int kk = 0; kk < 2; ++kk) {
        unsigned Brh[4], Brl[4], Bih[4], Bil[4];
        #pragma unroll
        for (int j2 = 0; j2 < 4; ++j2) {
            int kyi = kk * 16 + 4 * kg + j2;
            uint2 dr = gre[kyi][cl]; Brh[j2] = dr.x; Brl[j2] = dr.y;
            uint2 di = gim[kyi][cl]; Bih[j2] = di.x; Bil[j2] = di.y;
        }
        bf16x8 brh = mk8(Brh[0], Brh[1], Brh[2], Brh[3]);
        bf16x8 brl = mk8(Brl[0], Brl[1], Brl[2], Brl[3]);
        bf16x8 bih = mk8(Bih[0], Bih[1], Bih[2], Bih[3]);
        bf16x8 bil = mk8(Bil[0], Bil[1], Bil[2], Bil[3]);
        #pragma unroll
        for (int m = 0; m < 4; ++m) {
            int h = (wv * 4 + m) * 16 + cl;  // A row
            unsigned Ah[4], Al[4];
            #pragma unroll
            for (int j2 = 0; j2 < 4; ++j2) {
                int kyi = kk * 16 + 4 * kg + j2;
                int ky  = (kk == 0) ? kyi : (kyi + 224);
                uint2 t = twbf[(ky * h) & 255];
                Ah[j2] = t.x; Al[j2] = t.y;
            }
            bf16x8 ah = mk8(Ah[0], Ah[1], Ah[2], Ah[3]);
            bf16x8 al = mk8(Al[0], Al[1], Al[2], Al[3]);
            accR[m] = __builtin_amdgcn_mfma_f32_16x16x32_bf16(al, brl, accR[m], 0, 0, 0);
            accR[m] = __builtin_amdgcn_mfma_f32_16x16x32_bf16(ah, brl, accR[m], 0, 0, 0);
            accR[m] = __builtin_amdgcn_mfma_f32_16x16x32_bf16(al, brh, accR[m], 0, 0, 0);
            accR[m] = __builtin_amdgcn_mfma_f32_16x16x32_bf16(ah, brh, accR[m], 0, 0, 0);
            accI[m] = __builtin_amdgcn_mfma_f32_16x16x32_bf16(al, bil, accI[m], 0, 0, 0);
            accI[m] = __builtin_amdgcn_mfma_f32_16x16x32_bf16(ah, bil, accI[m], 0, 0, 0);
            accI[m] = __builtin_amdgcn_mfma_f32_16x16x32_bf16(al, bih, accI[m], 0, 0, 0);
            accI[m] = __builtin_amdgcn_mfma_f32_16x16x32_bf16(ah, bih, accI[m], 0, 0, 0);
        }
    }
    float sc = (cl == 0 ? 1.0f : 2.0f) * (1.0f / 65536.0f);
    float2* tp = (float2*)T;
    #pragma unroll
    for (int m = 0; m < 4; ++m) {
        #pragma unroll
        for (int q = 0; q < 4; ++q) {
            int h = (wv * 4 + m) * 16 + 4 * kg + q;
            tp[((size_t)bo * 256 + h) * 16 + cl] =
                make_float2(accR[m][q] * sc, accI[m][q] * sc);
        }
    }
}

// ---------------------------------------------------------------------------
// K6 (r27): inverse W-DFT + 1x1 conv + GeLU + skip, split-bf16 activations.
// Bx fragments: direct ushort loads from hi/lo planes (zero repack VALU);
// skip reconstructed hi+lo (rel err ~2^-17); epilogue writes split Y.
// In-place X/Y aliasing still safe (block reads its rows before writing).
// ---------------------------------------------------------------------------
__global__ __launch_bounds__(256)
void k_invw_conv(const float* __restrict__ T, const unsigned short* X, int ae,
                 const float* __restrict__ cw, const float* __restrict__ cb,
                 const unsigned short* __restrict__ skip, unsigned short* Y,
                 const float2* __restrict__ twg) {
    __shared__ float2 tw[256];
    __shared__ float2 tsh[32][17];           // +1 pad: conflict-light A-build reads
    int tid = threadIdx.x;
    tw[tid] = twg[tid];
    int b  = blockIdx.x >> 8;
    int hh = blockIdx.x & 255;
    const float2* tp = (const float2*)T;
    for (int n = tid; n < 512; n += 256) {
        int o = n >> 4, kx = n & 15;
        tsh[o][kx] = tp[(((size_t)(b * 32 + o)) * 256 + hh) * 16 + kx];
    }
    __syncthreads();
    int wv = tid >> 6, lane = tid & 63;
    int kg = lane >> 4, cl = lane & 15;

    // ---- A fragments (row o = mt*16 + cl, k = 8*kg + j) ----
    bf16x8 Ash[2], Asl[2];                   // spectral hi/lo
    bf16x8 Ach[2], Acl2[2];                  // conv hi/lo
    #pragma unroll
    for (int mt = 0; mt < 2; ++mt) {
        int o = mt * 16 + cl;
        const float4* cwp = (const float4*)(cw + o * 32 + 8 * kg);
        float4 c0 = cwp[0], c1 = cwp[1];
        float cvv[8] = {c0.x, c0.y, c0.z, c0.w, c1.x, c1.y, c1.z, c1.w};
        #pragma unroll
        for (int j = 0; j < 8; ++j) {
            int k = 8 * kg + j;
            float2 tv = tsh[o][k >> 1];
            float v = (k & 1) ? -tv.y : tv.x;
            __bf16 hv = (__bf16)v;
            Ash[mt][j] = hv;
            Asl[mt][j] = (__bf16)(v - (float)hv);
            float cv = cvv[j];
            __bf16 hc = (__bf16)cv;
            Ach[mt][j]  = hc;
            Acl2[mt][j] = (__bf16)(cv - (float)hc);
        }
    }

    // ---- accumulators, bias as C-init (row o = 16*mt + 4*kg + q) ----
    f32x4 acc[2][4];
    #pragma unroll
    for (int mt = 0; mt < 2; ++mt)
        #pragma unroll
        for (int nt = 0; nt < 4; ++nt)
            #pragma unroll
            for (int q = 0; q < 4; ++q)
                acc[mt][nt][q] = cb[mt * 16 + 4 * kg + q];

    const unsigned short* xbh = X + (size_t)b * CHW_ + (size_t)hh * W_;
    const unsigned short* xbl = xbh + (size_t)ae;
    #pragma unroll
    for (int nt = 0; nt < 4; ++nt) {
        int w = 64 * wv + 16 * nt + cl;
        bf16x8 Bth, Btl, Bxh, Bxl;
        #pragma unroll
        for (int j = 0; j < 8; ++j) {
            int k = 8 * kg + j;
            float2 cs = tw[((k >> 1) * w) & 255];
            float v = (k & 1) ? cs.y : cs.x;
            __bf16 hv = (__bf16)v;
            Bth[j] = hv;
            Btl[j] = (__bf16)(v - (float)hv);
            size_t xi = (size_t)k * HW_ + w;
            Bxh[j] = bfval(xbh[xi]);
            Bxl[j] = bfval(xbl[xi]);
        }
        #pragma unroll
        for (int mt = 0; mt < 2; ++mt) {
            acc[mt][nt] = __builtin_amdgcn_mfma_f32_16x16x32_bf16(Asl[mt],  Btl, acc[mt][nt], 0, 0, 0);
            acc[mt][nt] = __builtin_amdgcn_mfma_f32_16x16x32_bf16(Ash[mt],  Btl, acc[mt][nt], 0, 0, 0);
            acc[mt][nt] = __builtin_amdgcn_mfma_f32_16x16x32_bf16(Asl[mt],  Bth, acc[mt][nt], 0, 0, 0);
            acc[mt][nt] = __builtin_amdgcn_mfma_f32_16x16x32_bf16(Ash[mt],  Bth, acc[mt][nt], 0, 0, 0);
            acc[mt][nt] = __builtin_amdgcn_mfma_f32_16x16x32_bf16(Acl2[mt], Bxl, acc[mt][nt], 0, 0, 0);
            acc[mt][nt] = __builtin_amdgcn_mfma_f32_16x16x32_bf16(Ach[mt],  Bxl, acc[mt][nt], 0, 0, 0);
            acc[mt][nt] = __builtin_amdgcn_mfma_f32_16x16x32_bf16(Acl2[mt], Bxh, acc[mt][nt], 0, 0, 0);
            acc[mt][nt] = __builtin_amdgcn_mfma_f32_16x16x32_bf16(Ach[mt],  Bxh, acc[mt][nt], 0, 0, 0);
        }
    }

    // ---- epilogue: GeLU (+skip), split-bf16 stores ----
    const bool hasSkip = (skip != nullptr);
    #pragma unroll
    for (int mt = 0; mt < 2; ++mt) {
        #pragma unroll
        for (int q = 0; q < 4; ++q) {
            int o = 16 * mt + 4 * kg + q;
            size_t rowbase = (size_t)b * CHW_ + (size_t)o * HW_ + (size_t)hh * W_;
            #pragma unroll
            for (int nt = 0; nt < 4; ++nt) {
                int w = 64 * wv + 16 * nt + cl;
                size_t idx = rowbase + w;
                float g = gelu_exact(acc[mt][nt][q]);
                if (hasSkip)
                    g += (float)bfval(skip[idx]) + (float)bfval(skip[(size_t)ae + idx]);
                __bf16 gh = (__bf16)g;
                Y[idx]              = bfbits(gh);
                Y[(size_t)ae + idx] = bfbits((__bf16)(g - (float)gh));
            }
        }
    }
}

// ---------------------------------------------------------------------------
// K7a (r24): W1 fragment-pack prep into dead global (L2-hot for k_mlp).
// ---------------------------------------------------------------------------
__global__ __launch_bounds__(256)
void k_w1prep(const float* __restrict__ fc1_w, uint2* __restrict__ w1g) {
    int f = blockIdx.x * 256 + threadIdx.x;  // 0..2047
    int j2 = f & 3, cl = (f >> 2) & 15, kg = (f >> 6) & 3, nt = f >> 8;
    int d = nt * 16 + cl, k0 = 8 * kg + 2 * j2;
    w1g[f] = splitpack(fc1_w[k0 * 128 + d], fc1_w[(k0 + 1) * 128 + d]);
}

// ---------------------------------------------------------------------------
// K7 (r27): MLP head; X split-bf16 -> A fragments are direct loads (zero
// repack). Otherwise the r24 body (measured 70 us).
// ---------------------------------------------------------------------------
__global__ __launch_bounds__(256)
void k_mlp(const unsigned short* __restrict__ X, int ae,
           const uint2* __restrict__ w1g,
           const float* __restrict__ fc1_b, const float* __restrict__ fc2_w,
           const float* __restrict__ fc2_b, float* __restrict__ outb, int nChunks) {
    __shared__ float bsh[128];
    __shared__ float w2sh[640];
    __shared__ float Gsh[64][133];           // 34 KB, stride 133
    int tid = threadIdx.x;
    if (tid < 128) bsh[tid] = fc1_b[tid];
    for (int f = tid; f < 640; f += 256) w2sh[f] = fc2_w[f];
    float b2[5];
    #pragma unroll
    for (int s = 0; s < 5; ++s) b2[s] = fc2_b[s];
    int wv = tid >> 6, lane = tid & 63, kg = lane >> 4, cl = lane & 15;
    int ploc2 = tid >> 2, dq = tid & 3;      // phase-2: 4 threads per pixel
    __syncthreads();
    // ---- prefetch first chunk's X slice (hi+lo) into registers ----
    unsigned short xrh[8], xrl[8];
    {
        int c0 = blockIdx.x;
        if (c0 < nChunks) {
            int P0 = c0 * 64;
            const unsigned short* xp = X + (size_t)(P0 >> 16) * CHW_
                + (size_t)(8 * kg) * HW_ + ((P0 & 0xFFFF) + wv * 16 + cl);
            #pragma unroll
            for (int j = 0; j < 8; ++j) {
                xrh[j] = xp[(size_t)j * HW_];
                xrl[j] = xp[(size_t)ae + (size_t)j * HW_];
            }
        }
    }
    for (int chunk = blockIdx.x; chunk < nChunks; chunk += gridDim.x) {
        int P0 = chunk * 64;                 // 64 | 65536 -> never crosses image
        // ---- phase 1: A-build from prefetched regs (direct bitcast) ----
        bf16x8 Ah, Al;
        #pragma unroll
        for (int j = 0; j < 8; ++j) {
            Ah[j] = bfval(xrh[j]);
            Al[j] = bfval(xrl[j]);
        }
        int nc = chunk + gridDim.x;
        if (nc < nChunks) {
            int P1 = nc * 64;
            const unsigned short* xp = X + (size_t)(P1 >> 16) * CHW_
                + (size_t)(8 * kg) * HW_ + ((P1 & 0xFFFF) + wv * 16 + cl);
            #pragma unroll
            for (int j = 0; j < 8; ++j) {
                xrh[j] = xp[(size_t)j * HW_];
                xrl[j] = xp[(size_t)ae + (size_t)j * HW_];
            }
        }
        // ---- fc1 MFMA + GeLU -> Gsh ----
        #pragma unroll
        for (int nt = 0; nt < 8; ++nt) {
            const uint2* wp = &w1g[((nt * 4 + kg) * 16 + cl) * 4];
            uint2 q0 = wp[0], q1 = wp[1], q2 = wp[2], q3 = wp[3];
            bf16x8 Bh = mk8(q0.x, q1.x, q2.x, q3.x);
            bf16x8 Bl = mk8(q0.y, q1.y, q2.y, q3.y);
            float bv = bsh[nt * 16 + cl];
            f32x4 acc = {bv, bv, bv, bv};
            acc = __builtin_amdgcn_mfma_f32_16x16x32_bf16(Al, Bl, acc, 0, 0, 0);
            acc = __builtin_amdgcn_mfma_f32_16x16x32_bf16(Ah, Bl, acc, 0, 0, 0);
            acc = __builtin_amdgcn_mfma_f32_16x16x32_bf16(Al, Bh, acc, 0, 0, 0);
            acc = __builtin_amdgcn_mfma_f32_16x16x32_bf16(Ah, Bh, acc, 0, 0, 0);
            #pragma unroll
            for (int q = 0; q < 4; ++q)
                Gsh[wv * 16 + 4 * kg + q][nt * 16 + cl] = gelu_exact(acc[q]);
        }
        __syncthreads();
        // ---- phase 2: fc2 f32 from LDS + 4-lane reduce + store ----
        {
            float a5[5] = {0.f, 0.f, 0.f, 0.f, 0.f};
            #pragma unroll 8
            for (int j = 0; j < 32; ++j) {
                int d = dq + 4 * j;
                float gv = Gsh[ploc2][d];
                #pragma unroll
                for (int s = 0; s < 5; ++s) a5[s] += gv * w2sh[d * 5 + s];
            }
            #pragma unroll
            for (int s = 0; s < 5; ++s) {
                a5[s] += __shfl_xor(a5[s], 1);
                a5[s] += __shfl_xor(a5[s], 2);
            }
            if (dq == 0) {
                float* op = outb + (size_t)(P0 + ploc2) * 5;
                #pragma unroll
                for (int s = 0; s < 5; ++s) op[s] = a5[s] + b2[s];
            }
        }
        __syncthreads();                     // Gsh reused next chunk
    }
}

// ---------------------------------------------------------------------------
extern "C" void kernel_launch(void* const* d_in, const int* in_sizes, int n_in,
                              void* d_out, int out_size, void* d_ws, size_t ws_size,
                              hipStream_t stream) {
    const float* x      = (const float*)d_in[0];
    const float* fc0_w  = (const float*)d_in[1];
    const float* fc0_b  = (const float*)d_in[2];
    const float* w1     = (const float*)d_in[3];
    const float* w2     = (const float*)d_in[4];
    const float* conv_w = (const float*)d_in[5];
    const float* conv_b = (const float*)d_in[6];
    const float* fc1_w  = (const float*)d_in[7];
    const float* fc1_b  = (const float*)d_in[8];
    const float* fc2_w  = (const float*)d_in[9];
    const float* fc2_b  = (const float*)d_in[10];
    float* out = (float*)d_out;

    const size_t ACTb = 16777216;            // batched activation, elements
    const size_t ACTi = 2097152;             // per-image activation, elements
    const size_t STb = 2097152, Gb = 262144; // batched spectral, floats
    const size_t STi = 262144,  Gi = 32768;  // per-image spectral, floats

    if (ws_size >= 2 * ACTb * sizeof(float)) {
        // ---- BATCHED PATH. A0,A1 split-bf16 in ws (same 134 MB footprint:
        // each buffer = hi[ACTb] + lo[ACTb] ushorts = ACTb*4 bytes).
        // ST+G+tables pack into d_out, all dead before k_mlp rewrites out.
        unsigned short* A0u = (unsigned short*)d_ws;
        unsigned short* A1u = A0u + 2 * ACTb;
        float* ST = out;
        float* G  = ST + STb;
        float* TBL = G + Gb;                 // 9,728 floats of tables
        unsigned short* twfg = (unsigned short*)TBL;        // 8192 floats (32 KB)
        uint2* twbfg = (uint2*)(TBL + 8192);                // 512 floats
        float2* twg  = (float2*)(TBL + 8704);               // 512 floats

        k_twprep<<<32, 256, 0, stream>>>(twfg, twbfg, twg);
        k_lift<<<2048, 256, 0, stream>>>(x, fc0_w, fc0_b, A0u, (int)ACTb);
        auto layer = [&](int l, const unsigned short* Xin, unsigned short* Yout,
                         const unsigned short* skip) {
            k_dftw_dfth<<<256, 512, 0, stream>>>(Xin, (int)ACTb, G, twfg, twbfg);
            k_mix_idfth<<<256, 256, 0, stream>>>(G, w1 + (size_t)l * 524288,
                                                 w2 + (size_t)l * 524288, ST, twbfg);
            k_invw_conv<<<2048, 256, 0, stream>>>(ST, Xin, (int)ACTb,
                                                  conv_w + (size_t)l * 1024,
                                                  conv_b + (size_t)l * 32, skip, Yout,
                                                  twg);
        };
        layer(0, A0u, A1u, nullptr);   // A1 = h0
        layer(1, A0u, A0u, nullptr);   // in-place (per-pixel safe)
        layer(2, A0u, A0u, A1u);       // in-place, +h0
        layer(3, A0u, A1u, nullptr);   // A1 = h1 (h0 dead)
        layer(4, A0u, A0u, nullptr);   // in-place
        layer(5, A0u, A0u, A1u);       // in-place, +h1
        // A1 (h1) is dead after layer 5 -> stage W1 fragment packs there.
        k_w1prep<<<8, 256, 0, stream>>>(fc1_w, (uint2*)A1u);
        k_mlp<<<2048, 256, 0, stream>>>(A0u, (int)ACTb, (const uint2*)A1u,
                                        fc1_b, fc2_w, fc2_b, out, 8192);

    } else if (ws_size >= (3 * ACTi + STi + 2 * Gi) * sizeof(float)) {
        // ---- PER-IMAGE PATH (same kernels, rebased pointers).
        // A0/A1/A2 split-bf16 (each ACTi*4 bytes); ST/G/tables after.
        unsigned short* A0u = (unsigned short*)d_ws;
        unsigned short* A1u = A0u + 2 * ACTi;
        unsigned short* A2u = A0u + 4 * ACTi;
        float* ST = (float*)(A0u + 6 * ACTi);   // byte offset 3*ACTi*4, 16B-aligned
        float* G  = ST + STi;
        float* TBL = G + Gi;
        unsigned short* twfg = (unsigned short*)TBL;
        uint2* twbfg = (uint2*)(TBL + 8192);
        float2* twg  = (float2*)(TBL + 8704);

        k_twprep<<<32, 256, 0, stream>>>(twfg, twbfg, twg);
        auto layer = [&](int l, const unsigned short* Xin, unsigned short* Yout,
                         const unsigned short* skip) {
            k_dftw_dfth<<<32, 512, 0, stream>>>(Xin, (int)ACTi, G, twfg, twbfg);
            k_mix_idfth<<<32, 256, 0, stream>>>(G, w1 + (size_t)l * 524288,
                                                w2 + (size_t)l * 524288, ST, twbfg);
            k_invw_conv<<<256, 256, 0, stream>>>(ST, Xin, (int)ACTi,
                                                 conv_w + (size_t)l * 1024,
                                                 conv_b + (size_t)l * 32, skip, Yout,
                                                 twg);
        };
        for (int b = 0; b < 8; ++b) {
            k_lift<<<256, 256, 0, stream>>>(x + (size_t)b * HW_ * 10, fc0_w, fc0_b,
                                            A0u, (int)ACTi);
            layer(0, A0u, A2u, nullptr);   // A2 = h0
            layer(1, A0u, A1u, nullptr);
            layer(2, A1u, A0u, A2u);       // +h0
            layer(3, A0u, A2u, nullptr);   // A2 = h1
            layer(4, A0u, A1u, nullptr);
            layer(5, A1u, A0u, A2u);       // +h1
            // ST dead after layer 5's invw -> stage W1 packs there.
            k_w1prep<<<8, 256, 0, stream>>>(fc1_w, (uint2*)ST);
            k_mlp<<<1024, 256, 0, stream>>>(A0u, (int)ACTi, (const uint2*)ST,
                                            fc1_b, fc2_w, fc2_b,
                                            out + (size_t)b * 327680, 1024);
        }
    } else {
        k_probe<<<1, 64, 0, stream>>>(out, (float)(ws_size >> 10));
    }
}

// Round 17
// 541.688 us; speedup vs baseline: 1.1099x; 1.1099x over previous
//
#include <hip/hip_runtime.h>
#include <math.h>

#define C_ 32
#define H_ 256
#define W_ 256
#define HW_ 65536
#define CHW_ 2097152          // one image's activation, floats
#define TWO_PI 6.28318530717958647692f

typedef __bf16 bf16x8 __attribute__((ext_vector_type(8)));
typedef float  f32x4  __attribute__((ext_vector_type(4)));

__device__ __forceinline__ bf16x8 as_bf16x8(uint4 u) {
    return __builtin_bit_cast(bf16x8, u);
}
__device__ __forceinline__ unsigned short bfbits(__bf16 h) {
    return __builtin_bit_cast(unsigned short, h);
}
__device__ __forceinline__ bf16x8 mk8(unsigned a, unsigned b, unsigned c, unsigned d) {
    return __builtin_bit_cast(bf16x8, make_uint4(a, b, c, d));
}
__device__ __forceinline__ unsigned rot16(unsigned v) { return (v >> 16) | (v << 16); }
// Split (x,y) into bf16 hi/lo packs: .x = xh|yh<<16, .y = xl|yl<<16.
__device__ __forceinline__ uint2 splitpack(float x, float y) {
    __bf16 xh = (__bf16)x, yh = (__bf16)y;
    float xl = x - (float)xh, yl = y - (float)yh;
    unsigned hi = (unsigned)bfbits(xh) | ((unsigned)bfbits(yh) << 16);
    unsigned lo = (unsigned)bfbits((__bf16)xl) | ((unsigned)bfbits((__bf16)yl) << 16);
    return make_uint2(hi, lo);
}

__device__ __forceinline__ float gelu_exact(float x) {
    return 0.5f * x * (1.0f + erff(x * 0.7071067811865475f));
}

__global__ void k_probe(float* __restrict__ out, float ws_kib) {
    if (threadIdx.x == 0 && blockIdx.x == 0) out[0] = ws_kib;
}

// ---------------------------------------------------------------------------
// K0 (r26): one-shot twiddle-table prep (fixed offsets, verified r26).
// ---------------------------------------------------------------------------
__global__ __launch_bounds__(256)
void k_twprep(unsigned short* __restrict__ twfg, uint2* __restrict__ twbfg,
              float2* __restrict__ twg) {
    int f = blockIdx.x * 256 + threadIdx.x;  // grid 32 -> 0..8191
    {
        int i  = f & 7;
        int c  = (f >> 3) & 15;              // kx
        int g  = (f >> 7) & 3;
        int nt = (f >> 9) & 1;               // 0: re (cos), 1: im (-sin)
        int kk = f >> 10;
        int k  = kk * 32 + 8 * g + i;        // w index
        int a  = (k * c) & 255;
        float ang = (float)a * (TWO_PI / 256.0f);
        float s_, c_; sincosf(ang, &s_, &c_);
        float val = nt ? -s_ : c_;
        __bf16 hi = (__bf16)val;
        __bf16 lo = (__bf16)(val - (float)hi);
        twfg[f]        = bfbits(hi);
        twfg[8192 + f] = bfbits(lo);
    }
    if (f < 256) {
        float a = TWO_PI * (1.0f / 256.0f) * (float)f;
        float s_, c_; sincosf(a, &s_, &c_);
        twbfg[f] = splitpack(c_, s_);
        twg[f]   = make_float2(c_, s_);
    }
}

// ---------------------------------------------------------------------------
// K1: lift (unchanged).
// ---------------------------------------------------------------------------
__global__ __launch_bounds__(256)
void k_lift(const float* __restrict__ xb, const float* __restrict__ fc0_w,
            const float* __restrict__ fc0_b, float* __restrict__ out) {
    __shared__ float wsh[12 * 32];
    __shared__ float bsh[32];
    int tid = threadIdx.x;
    for (int n = tid; n < 384; n += 256) wsh[n] = fc0_w[n];
    if (tid < 32) bsh[tid] = fc0_b[tid];
    __syncthreads();
    int p = blockIdx.x * 256 + tid;          // b<<16 | h<<8 | w
    int w = p & 255;
    int h = (p >> 8) & 255;
    float in[12];
    const float* xp = xb + (size_t)p * 10;
    #pragma unroll
    for (int t = 0; t < 10; ++t) in[t] = xp[t];
    in[10] = (float)h * (1.0f / 255.0f);
    in[11] = (float)w * (1.0f / 255.0f);
    float* op = out + (p & 0xFFFF) + (size_t)(p >> 16) * CHW_;
    #pragma unroll
    for (int c = 0; c < 32; ++c) {
        float acc = bsh[c];
        #pragma unroll
        for (int t = 0; t < 12; ++t) acc += in[t] * wsh[t * 32 + c];
        op[(size_t)c * HW_] = acc;
    }
}

// ---------------------------------------------------------------------------
// K2 (r26): FUSED forward W-DFT + H-DFT, slp-direct, tables from global.
// ---------------------------------------------------------------------------
__global__ __launch_bounds__(512)
void k_dftw_dfth(const float* __restrict__ X, float* __restrict__ G,
                 const unsigned short* __restrict__ twfg,
                 const uint2* __restrict__ twbfg) {
    __shared__ __align__(16) unsigned short twf[16384];   // [hi/lo][kk][nt][g][c][i]
    __shared__ uint2 twbf[256];
    __shared__ uint2 slp[256][17];                        // (re_h|im_h, re_l|im_l), +1 pad
    int tid = threadIdx.x;
    {
        const uint4* tf4 = (const uint4*)twfg;
        uint4* tw4 = (uint4*)twf;
        #pragma unroll
        for (int f = tid; f < 2048; f += 512) tw4[f] = tf4[f];
        if (tid < 256) twbf[tid] = twbfg[tid];
    }
    __syncthreads();
    int wv = tid >> 6, lane = tid & 63, kg = lane >> 4, cl = lane & 15;
    const uint4* twp = (const uint4*)twf;    // 2048 fragments of 8 bf16
    int bo = blockIdx.x;                     // b*32 + c
    const float* xp = X + (size_t)bo * HW_;
    // ---- phase A: W-DFT, 2 tiles (32 h-rows) per wave, slp-direct ----
    #pragma unroll
    for (int tt = 0; tt < 2; ++tt) {
        int t = wv * 2 + tt;                 // tile: rows h = t*16 .. t*16+15
        const float* xr = xp + (size_t)(t * 16 + cl) * 256 + 8 * kg;
        f32x4 acc0 = {0.f, 0.f, 0.f, 0.f};   // re[kx=cl]
        f32x4 acc1 = {0.f, 0.f, 0.f, 0.f};   // im[kx=cl]
        #pragma unroll
        for (int kk = 0; kk < 8; ++kk) {
            float4 a0 = *(const float4*)(xr + kk * 32);
            float4 a1 = *(const float4*)(xr + kk * 32 + 4);
            float xv[8] = {a0.x, a0.y, a0.z, a0.w, a1.x, a1.y, a1.z, a1.w};
            bf16x8 Ah, Al;
            #pragma unroll
            for (int i = 0; i < 8; ++i) {
                __bf16 h = (__bf16)xv[i];
                Ah[i] = h;
                Al[i] = (__bf16)(xv[i] - (float)h);
            }
            int base = kk * 128 + kg * 16 + cl;          // uint4 index, hi, nt=0
            bf16x8 Bh0 = as_bf16x8(twp[base]);
            bf16x8 Bh1 = as_bf16x8(twp[base + 64]);
            bf16x8 Bl0 = as_bf16x8(twp[base + 1024]);
            bf16x8 Bl1 = as_bf16x8(twp[base + 1088]);
            acc0 = __builtin_amdgcn_mfma_f32_16x16x32_bf16(Al, Bl0, acc0, 0, 0, 0);
            acc0 = __builtin_amdgcn_mfma_f32_16x16x32_bf16(Ah, Bl0, acc0, 0, 0, 0);
            acc0 = __builtin_amdgcn_mfma_f32_16x16x32_bf16(Al, Bh0, acc0, 0, 0, 0);
            acc0 = __builtin_amdgcn_mfma_f32_16x16x32_bf16(Ah, Bh0, acc0, 0, 0, 0);
            acc1 = __builtin_amdgcn_mfma_f32_16x16x32_bf16(Al, Bl1, acc1, 0, 0, 0);
            acc1 = __builtin_amdgcn_mfma_f32_16x16x32_bf16(Ah, Bl1, acc1, 0, 0, 0);
            acc1 = __builtin_amdgcn_mfma_f32_16x16x32_bf16(Al, Bh1, acc1, 0, 0, 0);
            acc1 = __builtin_amdgcn_mfma_f32_16x16x32_bf16(Ah, Bh1, acc1, 0, 0, 0);
        }
        #pragma unroll
        for (int q = 0; q < 4; ++q)
            slp[t * 16 + 4 * kg + q][cl] = splitpack(acc0[q], acc1[q]);
    }
    __syncthreads();
    // ---- phase B: H-DFT (r15 body), waves 0-3 only ----
    if (wv < 4) {
        int mt = wv >> 1, nt = wv & 1;       // m-tile, part (0=re,1=im)
        int kyi_row = mt * 16 + cl;
        int ky = (kyi_row < 16) ? kyi_row : (kyi_row + 224);
        f32x4 acc = {0.f, 0.f, 0.f, 0.f};
        #pragma unroll 4
        for (int kk = 0; kk < 16; ++kk) {
            unsigned Ah[4], Al[4], Bh[4], Bl[4];
            #pragma unroll
            for (int j2 = 0; j2 < 4; ++j2) {
                int h = kk * 16 + kg * 4 + j2;   // h index for k = kk*32+8kg+2j2
                uint2 t = twbf[(ky * h) & 255];
                Ah[j2] = t.x; Al[j2] = t.y;
                uint2 d = slp[h][cl];
                if (nt == 0) { Bh[j2] = d.x;                       Bl[j2] = d.y; }
                else         { Bh[j2] = rot16(d.x) ^ 0x80000000u;  Bl[j2] = rot16(d.y) ^ 0x80000000u; }
            }
            bf16x8 ah = mk8(Ah[0], Ah[1], Ah[2], Ah[3]);
            bf16x8 al = mk8(Al[0], Al[1], Al[2], Al[3]);
            bf16x8 bh = mk8(Bh[0], Bh[1], Bh[2], Bh[3]);
            bf16x8 bl = mk8(Bl[0], Bl[1], Bl[2], Bl[3]);
            acc = __builtin_amdgcn_mfma_f32_16x16x32_bf16(al, bl, acc, 0, 0, 0);
            acc = __builtin_amdgcn_mfma_f32_16x16x32_bf16(ah, bl, acc, 0, 0, 0);
            acc = __builtin_amdgcn_mfma_f32_16x16x32_bf16(al, bh, acc, 0, 0, 0);
            acc = __builtin_amdgcn_mfma_f32_16x16x32_bf16(ah, bh, acc, 0, 0, 0);
        }
        // D: row kyi = mt*16 + 4kg + q, col kx = cl; float idx = (f2idx)*2 + nt.
        float* gf = G + (((size_t)bo * 512 + (size_t)(mt * 16 + 4 * kg) * 16 + cl) * 2 + nt);
        #pragma unroll
        for (int q = 0; q < 4; ++q) gf[q * 32] = acc[q];
    }
}

// ---------------------------------------------------------------------------
// K5 (r26): FUSED channel-mix + inverse H-DFT, table from global.
// ---------------------------------------------------------------------------
__global__ __launch_bounds__(256)
void k_mix_idfth(const float* __restrict__ G, const float* __restrict__ w1,
                 const float* __restrict__ w2, float* __restrict__ T,
                 const uint2* __restrict__ twbfg) {
    __shared__ uint2 twbf[256];
    __shared__ uint2 gre[32][17];
    __shared__ uint2 gim[32][17];
    int tid = threadIdx.x;
    twbf[tid] = twbfg[tid];
    int bo = blockIdx.x;                     // b*32 + o (per-image path: b=0)
    int b = bo >> 5, o = bo & 31;
    // ---- phase 1: mix (2 elements/thread) ----
    {
        int kyi = tid >> 4, kx = tid & 15;   // kyi in 0..15; elem2 = kyi+16
        const float2* gp1 = (const float2*)G + (size_t)b * 16384 + (size_t)kyi * 16 + kx;
        const float2* gp2 = gp1 + 256;       // rows kyi+16
        const float2* wv1 = (const float2*)w1 + (((size_t)o) * 16 + kyi) * 16 + kx;
        const float2* wv2 = (const float2*)w2 + (((size_t)o) * 16 + kyi) * 16 + kx;
        float ar1 = 0.f, ai1 = 0.f, ar2 = 0.f, ai2 = 0.f;
        #pragma unroll
        for (int i = 0; i < 32; ++i) {
            float2 g1 = gp1[(size_t)i * 512];
            float2 g2 = gp2[(size_t)i * 512];
            float2 wa = wv1[(size_t)i * 8192];
            float2 wb = wv2[(size_t)i * 8192];
            ar1 += g1.x * wa.x - g1.y * wa.y;
            ai1 += g1.x * wa.y + g1.y * wa.x;
            ar2 += g2.x * wb.x - g2.y * wb.y;
            ai2 += g2.x * wb.y + g2.y * wb.x;
        }
        gre[kyi][kx]      = splitpack(ar1, -ai1);
        gim[kyi][kx]      = splitpack(ai1,  ar1);
        gre[kyi + 16][kx] = splitpack(ar2, -ai2);
        gim[kyi + 16][kx] = splitpack(ai2,  ar2);
    }
    __syncthreads();
    // ---- phase 2: idfth (r15 body) ----
    int wv = tid >> 6, lane = tid & 63, kg = lane >> 4, cl = lane & 15;
    f32x4 accR[4] = {{0,0,0,0},{0,0,0,0},{0,0,0,0},{0,0,0,0}};
    f32x4 accI[4] = {{0,0,0,0},{0,0,0,0},{0,0,0,0},{0,0,0,0}};
    #pragma unroll
    for (int kk = 0; kk < 2; ++kk) {
        unsigned Brh[4], Brl[4], Bih[4], Bil[4];
        #pragma unroll
        for (int j2 = 0; j2 < 4; ++j2) {
            int kyi = kk * 16 + 4 * kg + j2;
            uint2 dr = gre[kyi][cl]; Brh[j2] = dr.x; Brl[j2] = dr.y;
            uint2 di = gim[kyi][cl]; Bih[j2] = di.x; Bil[j2] = di.y;
        }
        bf16x8 brh = mk8(Brh[0], Brh[1], Brh[2], Brh[3]);
        bf16x8 brl = mk8(Brl[0], Brl[1], Brl[2], Brl[3]);
        bf16x8 bih = mk8(Bih[0], Bih[1], Bih[2], Bih[3]);
        bf16x8 bil = mk8(Bil[0], Bil[1], Bil[2], Bil[3]);
        #pragma unroll
        for (int m = 0; m < 4; ++m) {
            int h = (wv * 4 + m) * 16 + cl;  // A row
            unsigned Ah[4], Al[4];
            #pragma unroll
            for (int j2 = 0; j2 < 4; ++j2) {
                int kyi = kk * 16 + 4 * kg + j2;
                int ky  = (kk == 0) ? kyi : (kyi + 224);
                uint2 t = twbf[(ky * h) & 255];
                Ah[j2] = t.x; Al[j2] = t.y;
            }
            bf16x8 ah = mk8(Ah[0], Ah[1], Ah[2], Ah[3]);
            bf16x8 al = mk8(Al[0], Al[1], Al[2], Al[3]);
            accR[m] = __builtin_amdgcn_mfma_f32_16x16x32_bf16(al, brl, accR[m], 0, 0, 0);
            accR[m] = __builtin_amdgcn_mfma_f32_16x16x32_bf16(ah, brl, accR[m], 0, 0, 0);
            accR[m] = __builtin_amdgcn_mfma_f32_16x16x32_bf16(al, brh, accR[m], 0, 0, 0);
            accR[m] = __builtin_amdgcn_mfma_f32_16x16x32_bf16(ah, brh, accR[m], 0, 0, 0);
            accI[m] = __builtin_amdgcn_mfma_f32_16x16x32_bf16(al, bil, accI[m], 0, 0, 0);
            accI[m] = __builtin_amdgcn_mfma_f32_16x16x32_bf16(ah, bil, accI[m], 0, 0, 0);
            accI[m] = __builtin_amdgcn_mfma_f32_16x16x32_bf16(al, bih, accI[m], 0, 0, 0);
            accI[m] = __builtin_amdgcn_mfma_f32_16x16x32_bf16(ah, bih, accI[m], 0, 0, 0);
        }
    }
    float sc = (cl == 0 ? 1.0f : 2.0f) * (1.0f / 65536.0f);
    float2* tp = (float2*)T;
    #pragma unroll
    for (int m = 0; m < 4; ++m) {
        #pragma unroll
        for (int q = 0; q < 4; ++q) {
            int h = (wv * 4 + m) * 16 + 4 * kg + q;
            tp[((size_t)bo * 256 + h) * 16 + cl] =
                make_float2(accR[m][q] * sc, accI[m][q] * sc);
        }
    }
}

// ---------------------------------------------------------------------------
// K6 (r26): inverse W-DFT + 1x1 conv + GeLU + skip, table from global.
// ---------------------------------------------------------------------------
__global__ __launch_bounds__(256)
void k_invw_conv(const float* __restrict__ T, const float* X,
                 const float* __restrict__ cw, const float* __restrict__ cb,
                 const float* __restrict__ skip, float* Y,
                 const float2* __restrict__ twg) {
    __shared__ float2 tw[256];
    __shared__ float2 tsh[32][17];           // +1 pad: conflict-light A-build reads
    int tid = threadIdx.x;
    tw[tid] = twg[tid];
    int b  = blockIdx.x >> 8;
    int hh = blockIdx.x & 255;
    const float2* tp = (const float2*)T;
    for (int n = tid; n < 512; n += 256) {
        int o = n >> 4, kx = n & 15;
        tsh[o][kx] = tp[(((size_t)(b * 32 + o)) * 256 + hh) * 16 + kx];
    }
    __syncthreads();
    int wv = tid >> 6, lane = tid & 63;
    int kg = lane >> 4, cl = lane & 15;

    // ---- A fragments (row o = mt*16 + cl, k = 8*kg + j) ----
    bf16x8 Ash[2], Asl[2];                   // spectral hi/lo
    bf16x8 Ach[2], Acl2[2];                  // conv hi/lo
    #pragma unroll
    for (int mt = 0; mt < 2; ++mt) {
        int o = mt * 16 + cl;
        const float4* cwp = (const float4*)(cw + o * 32 + 8 * kg);
        float4 c0 = cwp[0], c1 = cwp[1];
        float cvv[8] = {c0.x, c0.y, c0.z, c0.w, c1.x, c1.y, c1.z, c1.w};
        #pragma unroll
        for (int j = 0; j < 8; ++j) {
            int k = 8 * kg + j;
            float2 tv = tsh[o][k >> 1];
            float v = (k & 1) ? -tv.y : tv.x;
            __bf16 hv = (__bf16)v;
            Ash[mt][j] = hv;
            Asl[mt][j] = (__bf16)(v - (float)hv);
            float cv = cvv[j];
            __bf16 hc = (__bf16)cv;
            Ach[mt][j]  = hc;
            Acl2[mt][j] = (__bf16)(cv - (float)hc);
        }
    }

    // ---- accumulators, bias as C-init (row o = 16*mt + 4*kg + q) ----
    f32x4 acc[2][4];
    #pragma unroll
    for (int mt = 0; mt < 2; ++mt)
        #pragma unroll
        for (int nt = 0; nt < 4; ++nt)
            #pragma unroll
            for (int q = 0; q < 4; ++q)
                acc[mt][nt][q] = cb[mt * 16 + 4 * kg + q];

    const float* xb = X + (size_t)b * CHW_ + (size_t)hh * W_;
    #pragma unroll
    for (int nt = 0; nt < 4; ++nt) {
        int w = 64 * wv + 16 * nt + cl;
        bf16x8 Bth, Btl, Bxh, Bxl;
        #pragma unroll
        for (int j = 0; j < 8; ++j) {
            int k = 8 * kg + j;
            float2 cs = tw[((k >> 1) * w) & 255];
            float v = (k & 1) ? cs.y : cs.x;
            __bf16 hv = (__bf16)v;
            Bth[j] = hv;
            Btl[j] = (__bf16)(v - (float)hv);
            float xv = xb[(size_t)k * HW_ + w];
            __bf16 hx = (__bf16)xv;
            Bxh[j] = hx;
            Bxl[j] = (__bf16)(xv - (float)hx);
        }
        #pragma unroll
        for (int mt = 0; mt < 2; ++mt) {
            acc[mt][nt] = __builtin_amdgcn_mfma_f32_16x16x32_bf16(Asl[mt],  Btl, acc[mt][nt], 0, 0, 0);
            acc[mt][nt] = __builtin_amdgcn_mfma_f32_16x16x32_bf16(Ash[mt],  Btl, acc[mt][nt], 0, 0, 0);
            acc[mt][nt] = __builtin_amdgcn_mfma_f32_16x16x32_bf16(Asl[mt],  Bth, acc[mt][nt], 0, 0, 0);
            acc[mt][nt] = __builtin_amdgcn_mfma_f32_16x16x32_bf16(Ash[mt],  Bth, acc[mt][nt], 0, 0, 0);
            acc[mt][nt] = __builtin_amdgcn_mfma_f32_16x16x32_bf16(Acl2[mt], Bxl, acc[mt][nt], 0, 0, 0);
            acc[mt][nt] = __builtin_amdgcn_mfma_f32_16x16x32_bf16(Ach[mt],  Bxl, acc[mt][nt], 0, 0, 0);
            acc[mt][nt] = __builtin_amdgcn_mfma_f32_16x16x32_bf16(Acl2[mt], Bxh, acc[mt][nt], 0, 0, 0);
            acc[mt][nt] = __builtin_amdgcn_mfma_f32_16x16x32_bf16(Ach[mt],  Bxh, acc[mt][nt], 0, 0, 0);
        }
    }

    // ---- epilogue: GeLU (+skip), coalesced stores ----
    const bool hasSkip = (skip != nullptr);
    #pragma unroll
    for (int mt = 0; mt < 2; ++mt) {
        #pragma unroll
        for (int q = 0; q < 4; ++q) {
            int o = 16 * mt + 4 * kg + q;
            size_t rowbase = (size_t)b * CHW_ + (size_t)o * HW_ + (size_t)hh * W_;
            #pragma unroll
            for (int nt = 0; nt < 4; ++nt) {
                int w = 64 * wv + 16 * nt + cl;
                float g = gelu_exact(acc[mt][nt][q]);
                if (hasSkip) g += skip[rowbase + w];
                Y[rowbase + w] = g;
            }
        }
    }
}

// ---------------------------------------------------------------------------
// K7a (r24): W1 fragment-pack prep into dead global (L2-hot for k_mlp).
// ---------------------------------------------------------------------------
__global__ __launch_bounds__(256)
void k_w1prep(const float* __restrict__ fc1_w, uint2* __restrict__ w1g) {
    int f = blockIdx.x * 256 + threadIdx.x;  // 0..2047
    int j2 = f & 3, cl = (f >> 2) & 15, kg = (f >> 6) & 3, nt = f >> 8;
    int d = nt * 16 + cl, k0 = 8 * kg + 2 * j2;
    w1g[f] = splitpack(fc1_w[k0 * 128 + d], fc1_w[(k0 + 1) * 128 + d]);
}

// ---------------------------------------------------------------------------
// K7 (r24, measured 70 us): MLP head, w1 fragments from L2-hot global.
// ---------------------------------------------------------------------------
__global__ __launch_bounds__(256)
void k_mlp(const float* __restrict__ X, const uint2* __restrict__ w1g,
           const float* __restrict__ fc1_b, const float* __restrict__ fc2_w,
           const float* __restrict__ fc2_b, float* __restrict__ outb, int nChunks) {
    __shared__ float bsh[128];
    __shared__ float w2sh[640];
    __shared__ float Gsh[64][133];           // 34 KB, stride 133
    int tid = threadIdx.x;
    if (tid < 128) bsh[tid] = fc1_b[tid];
    for (int f = tid; f < 640; f += 256) w2sh[f] = fc2_w[f];
    float b2[5];
    #pragma unroll
    for (int s = 0; s < 5; ++s) b2[s] = fc2_b[s];
    int wv = tid >> 6, lane = tid & 63, kg = lane >> 4, cl = lane & 15;
    int ploc2 = tid >> 2, dq = tid & 3;      // phase-2: 4 threads per pixel
    __syncthreads();
    // ---- prefetch first chunk's X slice into registers ----
    float xr[8];
    {
        int c0 = blockIdx.x;
        if (c0 < nChunks) {
            int P0 = c0 * 64;
            const float* xp = X + (size_t)(P0 >> 16) * CHW_ + (size_t)(8 * kg) * HW_
                            + ((P0 & 0xFFFF) + wv * 16 + cl);
            #pragma unroll
            for (int j = 0; j < 8; ++j) xr[j] = xp[(size_t)j * HW_];
        }
    }
    for (int chunk = blockIdx.x; chunk < nChunks; chunk += gridDim.x) {
        int P0 = chunk * 64;                 // 64 | 65536 -> never crosses image
        // ---- phase 1: A-build from prefetched regs, then prefetch next ----
        bf16x8 Ah, Al;
        #pragma unroll
        for (int j = 0; j < 8; ++j) {
            float v = xr[j];
            __bf16 h = (__bf16)v;
            Ah[j] = h;
            Al[j] = (__bf16)(v - (float)h);
        }
        int nc = chunk + gridDim.x;
        if (nc < nChunks) {
            int P1 = nc * 64;
            const float* xp = X + (size_t)(P1 >> 16) * CHW_ + (size_t)(8 * kg) * HW_
                            + ((P1 & 0xFFFF) + wv * 16 + cl);
            #pragma unroll
            for (int j = 0; j < 8; ++j) xr[j] = xp[(size_t)j * HW_];
        }
        // ---- fc1 MFMA + GeLU -> Gsh ----
        #pragma unroll
        for (int nt = 0; nt < 8; ++nt) {
            const uint2* wp = &w1g[((nt * 4 + kg) * 16 + cl) * 4];
            uint2 q0 = wp[0], q1 = wp[1], q2 = wp[2], q3 = wp[3];
            bf16x8 Bh = mk8(q0.x, q1.x, q2.x, q3.x);
            bf16x8 Bl = mk8(q0.y, q1.y, q2.y, q3.y);
            float bv = bsh[nt * 16 + cl];
            f32x4 acc = {bv, bv, bv, bv};
            acc = __builtin_amdgcn_mfma_f32_16x16x32_bf16(Al, Bl, acc, 0, 0, 0);
            acc = __builtin_amdgcn_mfma_f32_16x16x32_bf16(Ah, Bl, acc, 0, 0, 0);
            acc = __builtin_amdgcn_mfma_f32_16x16x32_bf16(Al, Bh, acc, 0, 0, 0);
            acc = __builtin_amdgcn_mfma_f32_16x16x32_bf16(Ah, Bh, acc, 0, 0, 0);
            #pragma unroll
            for (int q = 0; q < 4; ++q)
                Gsh[wv * 16 + 4 * kg + q][nt * 16 + cl] = gelu_exact(acc[q]);
        }
        __syncthreads();
        // ---- phase 2: fc2 f32 from LDS + 4-lane reduce + store ----
        {
            float a5[5] = {0.f, 0.f, 0.f, 0.f, 0.f};
            #pragma unroll 8
            for (int j = 0; j < 32; ++j) {
                int d = dq + 4 * j;
                float gv = Gsh[ploc2][d];
                #pragma unroll
                for (int s = 0; s < 5; ++s) a5[s] += gv * w2sh[d * 5 + s];
            }
            #pragma unroll
            for (int s = 0; s < 5; ++s) {
                a5[s] += __shfl_xor(a5[s], 1);
                a5[s] += __shfl_xor(a5[s], 2);
            }
            if (dq == 0) {
                float* op = outb + (size_t)(P0 + ploc2) * 5;
                #pragma unroll
                for (int s = 0; s < 5; ++s) op[s] = a5[s] + b2[s];
            }
        }
        __syncthreads();                     // Gsh reused next chunk
    }
}

// ---------------------------------------------------------------------------
extern "C" void kernel_launch(void* const* d_in, const int* in_sizes, int n_in,
                              void* d_out, int out_size, void* d_ws, size_t ws_size,
                              hipStream_t stream) {
    const float* x      = (const float*)d_in[0];
    const float* fc0_w  = (const float*)d_in[1];
    const float* fc0_b  = (const float*)d_in[2];
    const float* w1     = (const float*)d_in[3];
    const float* w2     = (const float*)d_in[4];
    const float* conv_w = (const float*)d_in[5];
    const float* conv_b = (const float*)d_in[6];
    const float* fc1_w  = (const float*)d_in[7];
    const float* fc1_b  = (const float*)d_in[8];
    const float* fc2_w  = (const float*)d_in[9];
    const float* fc2_b  = (const float*)d_in[10];
    float* out = (float*)d_out;

    const size_t ACTb = 16777216;            // batched activation, floats
    const size_t ACTi = 2097152;             // per-image activation, floats
    const size_t STb = 2097152, Gb = 262144; // batched spectral, floats
    const size_t STi = 262144,  Gi = 32768;  // per-image spectral, floats

    if (ws_size >= 2 * ACTb * sizeof(float)) {
        // ---- BATCHED PATH. A0,A1 in ws (128 MiB);
        // ST+G+tables pack into d_out (2,369,024 of 2,621,440 floats used),
        // all dead before k_mlp rewrites out.
        float* A0 = (float*)d_ws;
        float* A1 = A0 + ACTb;
        float* ST = out;
        float* G  = ST + STb;
        float* TBL = G + Gb;                 // 9,728 floats of tables
        unsigned short* twfg = (unsigned short*)TBL;        // 8192 floats (32 KB)
        uint2* twbfg = (uint2*)(TBL + 8192);                // 512 floats
        float2* twg  = (float2*)(TBL + 8704);               // 512 floats

        k_twprep<<<32, 256, 0, stream>>>(twfg, twbfg, twg);
        k_lift<<<2048, 256, 0, stream>>>(x, fc0_w, fc0_b, A0);
        auto layer = [&](int l, const float* Xin, float* Yout, const float* skip) {
            k_dftw_dfth<<<256, 512, 0, stream>>>(Xin, G, twfg, twbfg);
            k_mix_idfth<<<256, 256, 0, stream>>>(G, w1 + (size_t)l * 524288,
                                                 w2 + (size_t)l * 524288, ST, twbfg);
            k_invw_conv<<<2048, 256, 0, stream>>>(ST, Xin, conv_w + (size_t)l * 1024,
                                                  conv_b + (size_t)l * 32, skip, Yout,
                                                  twg);
        };
        layer(0, A0, A1, nullptr);   // A1 = h0
        layer(1, A0, A0, nullptr);   // in-place (per-pixel safe)
        layer(2, A0, A0, A1);        // in-place, +h0
        layer(3, A0, A1, nullptr);   // A1 = h1 (h0 dead)
        layer(4, A0, A0, nullptr);   // in-place
        layer(5, A0, A0, A1);        // in-place, +h1
        // A1 (h1) is dead after layer 5 -> stage W1 fragment packs there.
        k_w1prep<<<8, 256, 0, stream>>>(fc1_w, (uint2*)A1);
        k_mlp<<<2048, 256, 0, stream>>>(A0, (const uint2*)A1, fc1_b, fc2_w, fc2_b,
                                        out, 8192);

    } else if (ws_size >= (3 * ACTi + STi + 2 * Gi) * sizeof(float)) {
        // ---- PER-IMAGE PATH (fallback; same kernels, rebased pointers).
        // Tables live in the old G2 region (G + Gi, 32768 floats >= 9728).
        float* A0 = (float*)d_ws;
        float* A1 = A0 + ACTi;
        float* A2 = A1 + ACTi;
        float* ST = A2 + ACTi;
        float* G  = ST + STi;
        float* TBL = G + Gi;
        unsigned short* twfg = (unsigned short*)TBL;
        uint2* twbfg = (uint2*)(TBL + 8192);
        float2* twg  = (float2*)(TBL + 8704);

        k_twprep<<<32, 256, 0, stream>>>(twfg, twbfg, twg);
        auto layer = [&](int l, const float* Xin, float* Yout, const float* skip) {
            k_dftw_dfth<<<32, 512, 0, stream>>>(Xin, G, twfg, twbfg);
            k_mix_idfth<<<32, 256, 0, stream>>>(G, w1 + (size_t)l * 524288,
                                                w2 + (size_t)l * 524288, ST, twbfg);
            k_invw_conv<<<256, 256, 0, stream>>>(ST, Xin, conv_w + (size_t)l * 1024,
                                                 conv_b + (size_t)l * 32, skip, Yout,
                                                 twg);
        };
        for (int b = 0; b < 8; ++b) {
            k_lift<<<256, 256, 0, stream>>>(x + (size_t)b * HW_ * 10, fc0_w, fc0_b, A0);
            layer(0, A0, A2, nullptr);   // A2 = h0
            layer(1, A0, A1, nullptr);
            layer(2, A1, A0, A2);        // +h0
            layer(3, A0, A2, nullptr);   // A2 = h1
            layer(4, A0, A1, nullptr);
            layer(5, A1, A0, A2);        // +h1
            // ST dead after layer 5's invw -> stage W1 packs there.
            k_w1prep<<<8, 256, 0, stream>>>(fc1_w, (uint2*)ST);
            k_mlp<<<1024, 256, 0, stream>>>(A0, (const uint2*)ST, fc1_b, fc2_w,
                                            fc2_b, out + (size_t)b * 327680, 1024);
        }
    } else {
        k_probe<<<1, 64, 0, stream>>>(out, (float)(ws_size >> 10));
    }
}

// Round 18
// 541.585 us; speedup vs baseline: 1.1101x; 1.0002x over previous
//
#include <hip/hip_runtime.h>
#include <math.h>

#define C_ 32
#define H_ 256
#define W_ 256
#define HW_ 65536
#define CHW_ 2097152          // one image's activation, floats
#define HCW_ 8192             // one h-slab: 32 channels x 256 w
#define TWO_PI 6.28318530717958647692f

// Activation layout (r29): [b][h][c][w]  ->  b*CHW_ + h*8192 + c*256 + w.
// Pure storage permutation vs r26's [b][c][h][w]; all math bit-identical.

typedef __bf16 bf16x8 __attribute__((ext_vector_type(8)));
typedef float  f32x4  __attribute__((ext_vector_type(4)));

__device__ __forceinline__ bf16x8 as_bf16x8(uint4 u) {
    return __builtin_bit_cast(bf16x8, u);
}
__device__ __forceinline__ unsigned short bfbits(__bf16 h) {
    return __builtin_bit_cast(unsigned short, h);
}
__device__ __forceinline__ bf16x8 mk8(unsigned a, unsigned b, unsigned c, unsigned d) {
    return __builtin_bit_cast(bf16x8, make_uint4(a, b, c, d));
}
__device__ __forceinline__ unsigned rot16(unsigned v) { return (v >> 16) | (v << 16); }
// Split (x,y) into bf16 hi/lo packs: .x = xh|yh<<16, .y = xl|yl<<16.
__device__ __forceinline__ uint2 splitpack(float x, float y) {
    __bf16 xh = (__bf16)x, yh = (__bf16)y;
    float xl = x - (float)xh, yl = y - (float)yh;
    unsigned hi = (unsigned)bfbits(xh) | ((unsigned)bfbits(yh) << 16);
    unsigned lo = (unsigned)bfbits((__bf16)xl) | ((unsigned)bfbits((__bf16)yl) << 16);
    return make_uint2(hi, lo);
}

__device__ __forceinline__ float gelu_exact(float x) {
    return 0.5f * x * (1.0f + erff(x * 0.7071067811865475f));
}

__global__ void k_probe(float* __restrict__ out, float ws_kib) {
    if (threadIdx.x == 0 && blockIdx.x == 0) out[0] = ws_kib;
}

// ---------------------------------------------------------------------------
// K0 (r26): one-shot twiddle-table prep (fixed offsets, verified r26).
// ---------------------------------------------------------------------------
__global__ __launch_bounds__(256)
void k_twprep(unsigned short* __restrict__ twfg, uint2* __restrict__ twbfg,
              float2* __restrict__ twg) {
    int f = blockIdx.x * 256 + threadIdx.x;  // grid 32 -> 0..8191
    {
        int i  = f & 7;
        int c  = (f >> 3) & 15;              // kx
        int g  = (f >> 7) & 3;
        int nt = (f >> 9) & 1;               // 0: re (cos), 1: im (-sin)
        int kk = f >> 10;
        int k  = kk * 32 + 8 * g + i;        // w index
        int a  = (k * c) & 255;
        float ang = (float)a * (TWO_PI / 256.0f);
        float s_, c_; sincosf(ang, &s_, &c_);
        float val = nt ? -s_ : c_;
        __bf16 hi = (__bf16)val;
        __bf16 lo = (__bf16)(val - (float)hi);
        twfg[f]        = bfbits(hi);
        twfg[8192 + f] = bfbits(lo);
    }
    if (f < 256) {
        float a = TWO_PI * (1.0f / 256.0f) * (float)f;
        float s_, c_; sincosf(a, &s_, &c_);
        twbfg[f] = splitpack(c_, s_);
        twg[f]   = make_float2(c_, s_);
    }
}

// ---------------------------------------------------------------------------
// K1 (r29): lift, [h][c][w] output — c-stores now 1 KB stride (was 256 KB).
// ---------------------------------------------------------------------------
__global__ __launch_bounds__(256)
void k_lift(const float* __restrict__ xb, const float* __restrict__ fc0_w,
            const float* __restrict__ fc0_b, float* __restrict__ out) {
    __shared__ float wsh[12 * 32];
    __shared__ float bsh[32];
    int tid = threadIdx.x;
    for (int n = tid; n < 384; n += 256) wsh[n] = fc0_w[n];
    if (tid < 32) bsh[tid] = fc0_b[tid];
    __syncthreads();
    int p = blockIdx.x * 256 + tid;          // b<<16 | h<<8 | w
    int w = p & 255;
    int h = (p >> 8) & 255;
    float in[12];
    const float* xp = xb + (size_t)p * 10;
    #pragma unroll
    for (int t = 0; t < 10; ++t) in[t] = xp[t];
    in[10] = (float)h * (1.0f / 255.0f);
    in[11] = (float)w * (1.0f / 255.0f);
    float* op = out + (size_t)(p >> 16) * CHW_ + (size_t)h * HCW_ + w;
    #pragma unroll
    for (int c = 0; c < 32; ++c) {
        float acc = bsh[c];
        #pragma unroll
        for (int t = 0; t < 12; ++t) acc += in[t] * wsh[t * 32 + c];
        op[c * 256] = acc;
    }
}

// ---------------------------------------------------------------------------
// K2 (r29): FUSED forward W-DFT + H-DFT; X rows at h*8192 + c*256 (1 KB
// contiguous per row, 32 KB row stride). Otherwise the verified r26 body.
// ---------------------------------------------------------------------------
__global__ __launch_bounds__(512)
void k_dftw_dfth(const float* __restrict__ X, float* __restrict__ G,
                 const unsigned short* __restrict__ twfg,
                 const uint2* __restrict__ twbfg) {
    __shared__ __align__(16) unsigned short twf[16384];   // [hi/lo][kk][nt][g][c][i]
    __shared__ uint2 twbf[256];
    __shared__ uint2 slp[256][17];                        // (re_h|im_h, re_l|im_l), +1 pad
    int tid = threadIdx.x;
    {
        const uint4* tf4 = (const uint4*)twfg;
        uint4* tw4 = (uint4*)twf;
        #pragma unroll
        for (int f = tid; f < 2048; f += 512) tw4[f] = tf4[f];
        if (tid < 256) twbf[tid] = twbfg[tid];
    }
    __syncthreads();
    int wv = tid >> 6, lane = tid & 63, kg = lane >> 4, cl = lane & 15;
    const uint4* twp = (const uint4*)twf;    // 2048 fragments of 8 bf16
    int bo = blockIdx.x;                     // b*32 + c
    const float* xp = X + (size_t)(bo >> 5) * CHW_ + (size_t)(bo & 31) * 256;
    // ---- phase A: W-DFT, 2 tiles (32 h-rows) per wave, slp-direct ----
    #pragma unroll
    for (int tt = 0; tt < 2; ++tt) {
        int t = wv * 2 + tt;                 // tile: rows h = t*16 .. t*16+15
        const float* xr = xp + (size_t)(t * 16 + cl) * HCW_ + 8 * kg;
        f32x4 acc0 = {0.f, 0.f, 0.f, 0.f};   // re[kx=cl]
        f32x4 acc1 = {0.f, 0.f, 0.f, 0.f};   // im[kx=cl]
        #pragma unroll
        for (int kk = 0; kk < 8; ++kk) {
            float4 a0 = *(const float4*)(xr + kk * 32);
            float4 a1 = *(const float4*)(xr + kk * 32 + 4);
            float xv[8] = {a0.x, a0.y, a0.z, a0.w, a1.x, a1.y, a1.z, a1.w};
            bf16x8 Ah, Al;
            #pragma unroll
            for (int i = 0; i < 8; ++i) {
                __bf16 h = (__bf16)xv[i];
                Ah[i] = h;
                Al[i] = (__bf16)(xv[i] - (float)h);
            }
            int base = kk * 128 + kg * 16 + cl;          // uint4 index, hi, nt=0
            bf16x8 Bh0 = as_bf16x8(twp[base]);
            bf16x8 Bh1 = as_bf16x8(twp[base + 64]);
            bf16x8 Bl0 = as_bf16x8(twp[base + 1024]);
            bf16x8 Bl1 = as_bf16x8(twp[base + 1088]);
            acc0 = __builtin_amdgcn_mfma_f32_16x16x32_bf16(Al, Bl0, acc0, 0, 0, 0);
            acc0 = __builtin_amdgcn_mfma_f32_16x16x32_bf16(Ah, Bl0, acc0, 0, 0, 0);
            acc0 = __builtin_amdgcn_mfma_f32_16x16x32_bf16(Al, Bh0, acc0, 0, 0, 0);
            acc0 = __builtin_amdgcn_mfma_f32_16x16x32_bf16(Ah, Bh0, acc0, 0, 0, 0);
            acc1 = __builtin_amdgcn_mfma_f32_16x16x32_bf16(Al, Bl1, acc1, 0, 0, 0);
            acc1 = __builtin_amdgcn_mfma_f32_16x16x32_bf16(Ah, Bl1, acc1, 0, 0, 0);
            acc1 = __builtin_amdgcn_mfma_f32_16x16x32_bf16(Al, Bh1, acc1, 0, 0, 0);
            acc1 = __builtin_amdgcn_mfma_f32_16x16x32_bf16(Ah, Bh1, acc1, 0, 0, 0);
        }
        #pragma unroll
        for (int q = 0; q < 4; ++q)
            slp[t * 16 + 4 * kg + q][cl] = splitpack(acc0[q], acc1[q]);
    }
    __syncthreads();
    // ---- phase B: H-DFT (r15 body), waves 0-3 only ----
    if (wv < 4) {
        int mt = wv >> 1, nt = wv & 1;       // m-tile, part (0=re,1=im)
        int kyi_row = mt * 16 + cl;
        int ky = (kyi_row < 16) ? kyi_row : (kyi_row + 224);
        f32x4 acc = {0.f, 0.f, 0.f, 0.f};
        #pragma unroll 4
        for (int kk = 0; kk < 16; ++kk) {
            unsigned Ah[4], Al[4], Bh[4], Bl[4];
            #pragma unroll
            for (int j2 = 0; j2 < 4; ++j2) {
                int h = kk * 16 + kg * 4 + j2;   // h index for k = kk*32+8kg+2j2
                uint2 t = twbf[(ky * h) & 255];
                Ah[j2] = t.x; Al[j2] = t.y;
                uint2 d = slp[h][cl];
                if (nt == 0) { Bh[j2] = d.x;                       Bl[j2] = d.y; }
                else         { Bh[j2] = rot16(d.x) ^ 0x80000000u;  Bl[j2] = rot16(d.y) ^ 0x80000000u; }
            }
            bf16x8 ah = mk8(Ah[0], Ah[1], Ah[2], Ah[3]);
            bf16x8 al = mk8(Al[0], Al[1], Al[2], Al[3]);
            bf16x8 bh = mk8(Bh[0], Bh[1], Bh[2], Bh[3]);
            bf16x8 bl = mk8(Bl[0], Bl[1], Bl[2], Bl[3]);
            acc = __builtin_amdgcn_mfma_f32_16x16x32_bf16(al, bl, acc, 0, 0, 0);
            acc = __builtin_amdgcn_mfma_f32_16x16x32_bf16(ah, bl, acc, 0, 0, 0);
            acc = __builtin_amdgcn_mfma_f32_16x16x32_bf16(al, bh, acc, 0, 0, 0);
            acc = __builtin_amdgcn_mfma_f32_16x16x32_bf16(ah, bh, acc, 0, 0, 0);
        }
        // D: row kyi = mt*16 + 4kg + q, col kx = cl; float idx = (f2idx)*2 + nt.
        float* gf = G + (((size_t)bo * 512 + (size_t)(mt * 16 + 4 * kg) * 16 + cl) * 2 + nt);
        #pragma unroll
        for (int q = 0; q < 4; ++q) gf[q * 32] = acc[q];
    }
}

// ---------------------------------------------------------------------------
// K5 (r26, unchanged): FUSED channel-mix + inverse H-DFT, table from global.
// ---------------------------------------------------------------------------
__global__ __launch_bounds__(256)
void k_mix_idfth(const float* __restrict__ G, const float* __restrict__ w1,
                 const float* __restrict__ w2, float* __restrict__ T,
                 const uint2* __restrict__ twbfg) {
    __shared__ uint2 twbf[256];
    __shared__ uint2 gre[32][17];
    __shared__ uint2 gim[32][17];
    int tid = threadIdx.x;
    twbf[tid] = twbfg[tid];
    int bo = blockIdx.x;                     // b*32 + o (per-image path: b=0)
    int b = bo >> 5, o = bo & 31;
    // ---- phase 1: mix (2 elements/thread) ----
    {
        int kyi = tid >> 4, kx = tid & 15;   // kyi in 0..15; elem2 = kyi+16
        const float2* gp1 = (const float2*)G + (size_t)b * 16384 + (size_t)kyi * 16 + kx;
        const float2* gp2 = gp1 + 256;       // rows kyi+16
        const float2* wv1 = (const float2*)w1 + (((size_t)o) * 16 + kyi) * 16 + kx;
        const float2* wv2 = (const float2*)w2 + (((size_t)o) * 16 + kyi) * 16 + kx;
        float ar1 = 0.f, ai1 = 0.f, ar2 = 0.f, ai2 = 0.f;
        #pragma unroll
        for (int i = 0; i < 32; ++i) {
            float2 g1 = gp1[(size_t)i * 512];
            float2 g2 = gp2[(size_t)i * 512];
            float2 wa = wv1[(size_t)i * 8192];
            float2 wb = wv2[(size_t)i * 8192];
            ar1 += g1.x * wa.x - g1.y * wa.y;
            ai1 += g1.x * wa.y + g1.y * wa.x;
            ar2 += g2.x * wb.x - g2.y * wb.y;
            ai2 += g2.x * wb.y + g2.y * wb.x;
        }
        gre[kyi][kx]      = splitpack(ar1, -ai1);
        gim[kyi][kx]      = splitpack(ai1,  ar1);
        gre[kyi + 16][kx] = splitpack(ar2, -ai2);
        gim[kyi + 16][kx] = splitpack(ai2,  ar2);
    }
    __syncthreads();
    // ---- phase 2: idfth (r15 body) ----
    int wv = tid >> 6, lane = tid & 63, kg = lane >> 4, cl = lane & 15;
    f32x4 accR[4] = {{0,0,0,0},{0,0,0,0},{0,0,0,0},{0,0,0,0}};
    f32x4 accI[4] = {{0,0,0,0},{0,0,0,0},{0,0,0,0},{0,0,0,0}};
    #pragma unroll
    for (int kk = 0; kk < 2; ++kk) {
        unsigned Brh[4], Brl[4], Bih[4], Bil[4];
        #pragma unroll
        for (int j2 = 0; j2 < 4; ++j2) {
            int kyi = kk * 16 + 4 * kg + j2;
            uint2 dr = gre[kyi][cl]; Brh[j2] = dr.x; Brl[j2] = dr.y;
            uint2 di = gim[kyi][cl]; Bih[j2] = di.x; Bil[j2] = di.y;
        }
        bf16x8 brh = mk8(Brh[0], Brh[1], Brh[2], Brh[3]);
        bf16x8 brl = mk8(Brl[0], Brl[1], Brl[2], Brl[3]);
        bf16x8 bih = mk8(Bih[0], Bih[1], Bih[2], Bih[3]);
        bf16x8 bil = mk8(Bil[0], Bil[1], Bil[2], Bil[3]);
        #pragma unroll
        for (int m = 0; m < 4; ++m) {
            int h = (wv * 4 + m) * 16 + cl;  // A row
            unsigned Ah[4], Al[4];
            #pragma unroll
            for (int j2 = 0; j2 < 4; ++j2) {
                int kyi = kk * 16 + 4 * kg + j2;
                int ky  = (kk == 0) ? kyi : (kyi + 224);
                uint2 t = twbf[(ky * h) & 255];
                Ah[j2] = t.x; Al[j2] = t.y;
            }
            bf16x8 ah = mk8(Ah[0], Ah[1], Ah[2], Ah[3]);
            bf16x8 al = mk8(Al[0], Al[1], Al[2], Al[3]);
            accR[m] = __builtin_amdgcn_mfma_f32_16x16x32_bf16(al, brl, accR[m], 0, 0, 0);
            accR[m] = __builtin_amdgcn_mfma_f32_16x16x32_bf16(ah, brl, accR[m], 0, 0, 0);
            accR[m] = __builtin_amdgcn_mfma_f32_16x16x32_bf16(al, brh, accR[m], 0, 0, 0);
            accR[m] = __builtin_amdgcn_mfma_f32_16x16x32_bf16(ah, brh, accR[m], 0, 0, 0);
            accI[m] = __builtin_amdgcn_mfma_f32_16x16x32_bf16(al, bil, accI[m], 0, 0, 0);
            accI[m] = __builtin_amdgcn_mfma_f32_16x16x32_bf16(ah, bil, accI[m], 0, 0, 0);
            accI[m] = __builtin_amdgcn_mfma_f32_16x16x32_bf16(al, bih, accI[m], 0, 0, 0);
            accI[m] = __builtin_amdgcn_mfma_f32_16x16x32_bf16(ah, bih, accI[m], 0, 0, 0);
        }
    }
    float sc = (cl == 0 ? 1.0f : 2.0f) * (1.0f / 65536.0f);
    float2* tp = (float2*)T;
    #pragma unroll
    for (int m = 0; m < 4; ++m) {
        #pragma unroll
        for (int q = 0; q < 4; ++q) {
            int h = (wv * 4 + m) * 16 + 4 * kg + q;
            tp[((size_t)bo * 256 + h) * 16 + cl] =
                make_float2(accR[m][q] * sc, accI[m][q] * sc);
        }
    }
}

// ---------------------------------------------------------------------------
// K6 (r29): inverse W-DFT + 1x1 conv + GeLU + skip; X/Y/skip at [h][c][w] —
// the block's entire activation slice is one contiguous 32 KB region
// (was 32 lines at 256 KB stride). In-place safe: block reads its hh slab
// fully before the epilogue writes it.
// ---------------------------------------------------------------------------
__global__ __launch_bounds__(256)
void k_invw_conv(const float* __restrict__ T, const float* X,
                 const float* __restrict__ cw, const float* __restrict__ cb,
                 const float* __restrict__ skip, float* Y,
                 const float2* __restrict__ twg) {
    __shared__ float2 tw[256];
    __shared__ float2 tsh[32][17];           // +1 pad: conflict-light A-build reads
    int tid = threadIdx.x;
    tw[tid] = twg[tid];
    int b  = blockIdx.x >> 8;
    int hh = blockIdx.x & 255;
    const float2* tp = (const float2*)T;
    for (int n = tid; n < 512; n += 256) {
        int o = n >> 4, kx = n & 15;
        tsh[o][kx] = tp[(((size_t)(b * 32 + o)) * 256 + hh) * 16 + kx];
    }
    __syncthreads();
    int wv = tid >> 6, lane = tid & 63;
    int kg = lane >> 4, cl = lane & 15;

    // ---- A fragments (row o = mt*16 + cl, k = 8*kg + j) ----
    bf16x8 Ash[2], Asl[2];                   // spectral hi/lo
    bf16x8 Ach[2], Acl2[2];                  // conv hi/lo
    #pragma unroll
    for (int mt = 0; mt < 2; ++mt) {
        int o = mt * 16 + cl;
        const float4* cwp = (const float4*)(cw + o * 32 + 8 * kg);
        float4 c0 = cwp[0], c1 = cwp[1];
        float cvv[8] = {c0.x, c0.y, c0.z, c0.w, c1.x, c1.y, c1.z, c1.w};
        #pragma unroll
        for (int j = 0; j < 8; ++j) {
            int k = 8 * kg + j;
            float2 tv = tsh[o][k >> 1];
            float v = (k & 1) ? -tv.y : tv.x;
            __bf16 hv = (__bf16)v;
            Ash[mt][j] = hv;
            Asl[mt][j] = (__bf16)(v - (float)hv);
            float cv = cvv[j];
            __bf16 hc = (__bf16)cv;
            Ach[mt][j]  = hc;
            Acl2[mt][j] = (__bf16)(cv - (float)hc);
        }
    }

    // ---- accumulators, bias as C-init (row o = 16*mt + 4*kg + q) ----
    f32x4 acc[2][4];
    #pragma unroll
    for (int mt = 0; mt < 2; ++mt)
        #pragma unroll
        for (int nt = 0; nt < 4; ++nt)
            #pragma unroll
            for (int q = 0; q < 4; ++q)
                acc[mt][nt][q] = cb[mt * 16 + 4 * kg + q];

    const float* xb = X + (size_t)b * CHW_ + (size_t)hh * HCW_;
    #pragma unroll
    for (int nt = 0; nt < 4; ++nt) {
        int w = 64 * wv + 16 * nt + cl;
        bf16x8 Bth, Btl, Bxh, Bxl;
        #pragma unroll
        for (int j = 0; j < 8; ++j) {
            int k = 8 * kg + j;
            float2 cs = tw[((k >> 1) * w) & 255];
            float v = (k & 1) ? cs.y : cs.x;
            __bf16 hv = (__bf16)v;
            Bth[j] = hv;
            Btl[j] = (__bf16)(v - (float)hv);
            float xv = xb[k * 256 + w];
            __bf16 hx = (__bf16)xv;
            Bxh[j] = hx;
            Bxl[j] = (__bf16)(xv - (float)hx);
        }
        #pragma unroll
        for (int mt = 0; mt < 2; ++mt) {
            acc[mt][nt] = __builtin_amdgcn_mfma_f32_16x16x32_bf16(Asl[mt],  Btl, acc[mt][nt], 0, 0, 0);
            acc[mt][nt] = __builtin_amdgcn_mfma_f32_16x16x32_bf16(Ash[mt],  Btl, acc[mt][nt], 0, 0, 0);
            acc[mt][nt] = __builtin_amdgcn_mfma_f32_16x16x32_bf16(Asl[mt],  Bth, acc[mt][nt], 0, 0, 0);
            acc[mt][nt] = __builtin_amdgcn_mfma_f32_16x16x32_bf16(Ash[mt],  Bth, acc[mt][nt], 0, 0, 0);
            acc[mt][nt] = __builtin_amdgcn_mfma_f32_16x16x32_bf16(Acl2[mt], Bxl, acc[mt][nt], 0, 0, 0);
            acc[mt][nt] = __builtin_amdgcn_mfma_f32_16x16x32_bf16(Ach[mt],  Bxl, acc[mt][nt], 0, 0, 0);
            acc[mt][nt] = __builtin_amdgcn_mfma_f32_16x16x32_bf16(Acl2[mt], Bxh, acc[mt][nt], 0, 0, 0);
            acc[mt][nt] = __builtin_amdgcn_mfma_f32_16x16x32_bf16(Ach[mt],  Bxh, acc[mt][nt], 0, 0, 0);
        }
    }

    // ---- epilogue: GeLU (+skip), coalesced stores ----
    const bool hasSkip = (skip != nullptr);
    size_t slab = (size_t)b * CHW_ + (size_t)hh * HCW_;
    #pragma unroll
    for (int mt = 0; mt < 2; ++mt) {
        #pragma unroll
        for (int q = 0; q < 4; ++q) {
            int o = 16 * mt + 4 * kg + q;
            size_t rowbase = slab + (size_t)o * 256;
            #pragma unroll
            for (int nt = 0; nt < 4; ++nt) {
                int w = 64 * wv + 16 * nt + cl;
                float g = gelu_exact(acc[mt][nt][q]);
                if (hasSkip) g += skip[rowbase + w];
                Y[rowbase + w] = g;
            }
        }
    }
}

// ---------------------------------------------------------------------------
// K7a (r24): W1 fragment-pack prep into dead global (L2-hot for k_mlp).
// ---------------------------------------------------------------------------
__global__ __launch_bounds__(256)
void k_w1prep(const float* __restrict__ fc1_w, uint2* __restrict__ w1g) {
    int f = blockIdx.x * 256 + threadIdx.x;  // 0..2047
    int j2 = f & 3, cl = (f >> 2) & 15, kg = (f >> 6) & 3, nt = f >> 8;
    int d = nt * 16 + cl, k0 = 8 * kg + 2 * j2;
    w1g[f] = splitpack(fc1_w[k0 * 128 + d], fc1_w[(k0 + 1) * 128 + d]);
}

// ---------------------------------------------------------------------------
// K7 (r29): MLP head; X at [h][c][w] — each chunk's activation reads live in
// one contiguous 8 KB window (was 32 lines at 256 KB stride).
// ---------------------------------------------------------------------------
__global__ __launch_bounds__(256)
void k_mlp(const float* __restrict__ X, const uint2* __restrict__ w1g,
           const float* __restrict__ fc1_b, const float* __restrict__ fc2_w,
           const float* __restrict__ fc2_b, float* __restrict__ outb, int nChunks) {
    __shared__ float bsh[128];
    __shared__ float w2sh[640];
    __shared__ float Gsh[64][133];           // 34 KB, stride 133
    int tid = threadIdx.x;
    if (tid < 128) bsh[tid] = fc1_b[tid];
    for (int f = tid; f < 640; f += 256) w2sh[f] = fc2_w[f];
    float b2[5];
    #pragma unroll
    for (int s = 0; s < 5; ++s) b2[s] = fc2_b[s];
    int wv = tid >> 6, lane = tid & 63, kg = lane >> 4, cl = lane & 15;
    int ploc2 = tid >> 2, dq = tid & 3;      // phase-2: 4 threads per pixel
    __syncthreads();
    // ---- prefetch first chunk's X slice into registers ----
    float xr[8];
    {
        int c0 = blockIdx.x;
        if (c0 < nChunks) {
            int P0 = c0 * 64;
            int hw0 = P0 & 0xFFFF;
            const float* xp = X + (size_t)(P0 >> 16) * CHW_
                + (size_t)(hw0 >> 8) * HCW_ + (8 * kg) * 256
                + ((hw0 & 255) + wv * 16 + cl);
            #pragma unroll
            for (int j = 0; j < 8; ++j) xr[j] = xp[j * 256];
        }
    }
    for (int chunk = blockIdx.x; chunk < nChunks; chunk += gridDim.x) {
        int P0 = chunk * 64;                 // 64 | 65536 -> never crosses image
        // ---- phase 1: A-build from prefetched regs, then prefetch next ----
        bf16x8 Ah, Al;
        #pragma unroll
        for (int j = 0; j < 8; ++j) {
            float v = xr[j];
            __bf16 h = (__bf16)v;
            Ah[j] = h;
            Al[j] = (__bf16)(v - (float)h);
        }
        int nc = chunk + gridDim.x;
        if (nc < nChunks) {
            int P1 = nc * 64;
            int hw1 = P1 & 0xFFFF;
            const float* xp = X + (size_t)(P1 >> 16) * CHW_
                + (size_t)(hw1 >> 8) * HCW_ + (8 * kg) * 256
                + ((hw1 & 255) + wv * 16 + cl);
            #pragma unroll
            for (int j = 0; j < 8; ++j) xr[j] = xp[j * 256];
        }
        // ---- fc1 MFMA + GeLU -> Gsh ----
        #pragma unroll
        for (int nt = 0; nt < 8; ++nt) {
            const uint2* wp = &w1g[((nt * 4 + kg) * 16 + cl) * 4];
            uint2 q0 = wp[0], q1 = wp[1], q2 = wp[2], q3 = wp[3];
            bf16x8 Bh = mk8(q0.x, q1.x, q2.x, q3.x);
            bf16x8 Bl = mk8(q0.y, q1.y, q2.y, q3.y);
            float bv = bsh[nt * 16 + cl];
            f32x4 acc = {bv, bv, bv, bv};
            acc = __builtin_amdgcn_mfma_f32_16x16x32_bf16(Al, Bl, acc, 0, 0, 0);
            acc = __builtin_amdgcn_mfma_f32_16x16x32_bf16(Ah, Bl, acc, 0, 0, 0);
            acc = __builtin_amdgcn_mfma_f32_16x16x32_bf16(Al, Bh, acc, 0, 0, 0);
            acc = __builtin_amdgcn_mfma_f32_16x16x32_bf16(Ah, Bh, acc, 0, 0, 0);
            #pragma unroll
            for (int q = 0; q < 4; ++q)
                Gsh[wv * 16 + 4 * kg + q][nt * 16 + cl] = gelu_exact(acc[q]);
        }
        __syncthreads();
        // ---- phase 2: fc2 f32 from LDS + 4-lane reduce + store ----
        {
            float a5[5] = {0.f, 0.f, 0.f, 0.f, 0.f};
            #pragma unroll 8
            for (int j = 0; j < 32; ++j) {
                int d = dq + 4 * j;
                float gv = Gsh[ploc2][d];
                #pragma unroll
                for (int s = 0; s < 5; ++s) a5[s] += gv * w2sh[d * 5 + s];
            }
            #pragma unroll
            for (int s = 0; s < 5; ++s) {
                a5[s] += __shfl_xor(a5[s], 1);
                a5[s] += __shfl_xor(a5[s], 2);
            }
            if (dq == 0) {
                float* op = outb + (size_t)(P0 + ploc2) * 5;
                #pragma unroll
                for (int s = 0; s < 5; ++s) op[s] = a5[s] + b2[s];
            }
        }
        __syncthreads();                     // Gsh reused next chunk
    }
}

// ---------------------------------------------------------------------------
extern "C" void kernel_launch(void* const* d_in, const int* in_sizes, int n_in,
                              void* d_out, int out_size, void* d_ws, size_t ws_size,
                              hipStream_t stream) {
    const float* x      = (const float*)d_in[0];
    const float* fc0_w  = (const float*)d_in[1];
    const float* fc0_b  = (const float*)d_in[2];
    const float* w1     = (const float*)d_in[3];
    const float* w2     = (const float*)d_in[4];
    const float* conv_w = (const float*)d_in[5];
    const float* conv_b = (const float*)d_in[6];
    const float* fc1_w  = (const float*)d_in[7];
    const float* fc1_b  = (const float*)d_in[8];
    const float* fc2_w  = (const float*)d_in[9];
    const float* fc2_b  = (const float*)d_in[10];
    float* out = (float*)d_out;

    const size_t ACTb = 16777216;            // batched activation, floats
    const size_t ACTi = 2097152;             // per-image activation, floats
    const size_t STb = 2097152, Gb = 262144; // batched spectral, floats
    const size_t STi = 262144,  Gi = 32768;  // per-image spectral, floats

    if (ws_size >= 2 * ACTb * sizeof(float)) {
        // ---- BATCHED PATH. A0,A1 in ws (128 MiB);
        // ST+G+tables pack into d_out, all dead before k_mlp rewrites out.
        float* A0 = (float*)d_ws;
        float* A1 = A0 + ACTb;
        float* ST = out;
        float* G  = ST + STb;
        float* TBL = G + Gb;                 // 9,728 floats of tables
        unsigned short* twfg = (unsigned short*)TBL;        // 8192 floats (32 KB)
        uint2* twbfg = (uint2*)(TBL + 8192);                // 512 floats
        float2* twg  = (float2*)(TBL + 8704);               // 512 floats

        k_twprep<<<32, 256, 0, stream>>>(twfg, twbfg, twg);
        k_lift<<<2048, 256, 0, stream>>>(x, fc0_w, fc0_b, A0);
        auto layer = [&](int l, const float* Xin, float* Yout, const float* skip) {
            k_dftw_dfth<<<256, 512, 0, stream>>>(Xin, G, twfg, twbfg);
            k_mix_idfth<<<256, 256, 0, stream>>>(G, w1 + (size_t)l * 524288,
                                                 w2 + (size_t)l * 524288, ST, twbfg);
            k_invw_conv<<<2048, 256, 0, stream>>>(ST, Xin, conv_w + (size_t)l * 1024,
                                                  conv_b + (size_t)l * 32, skip, Yout,
                                                  twg);
        };
        layer(0, A0, A1, nullptr);   // A1 = h0
        layer(1, A0, A0, nullptr);   // in-place (per-pixel safe)
        layer(2, A0, A0, A1);        // in-place, +h0
        layer(3, A0, A1, nullptr);   // A1 = h1 (h0 dead)
        layer(4, A0, A0, nullptr);   // in-place
        layer(5, A0, A0, A1);        // in-place, +h1
        // A1 (h1) is dead after layer 5 -> stage W1 fragment packs there.
        k_w1prep<<<8, 256, 0, stream>>>(fc1_w, (uint2*)A1);
        k_mlp<<<2048, 256, 0, stream>>>(A0, (const uint2*)A1, fc1_b, fc2_w, fc2_b,
                                        out, 8192);

    } else if (ws_size >= (3 * ACTi + STi + 2 * Gi) * sizeof(float)) {
        // ---- PER-IMAGE PATH (fallback; same kernels, rebased pointers).
        float* A0 = (float*)d_ws;
        float* A1 = A0 + ACTi;
        float* A2 = A1 + ACTi;
        float* ST = A2 + ACTi;
        float* G  = ST + STi;
        float* TBL = G + Gi;
        unsigned short* twfg = (unsigned short*)TBL;
        uint2* twbfg = (uint2*)(TBL + 8192);
        float2* twg  = (float2*)(TBL + 8704);

        k_twprep<<<32, 256, 0, stream>>>(twfg, twbfg, twg);
        auto layer = [&](int l, const float* Xin, float* Yout, const float* skip) {
            k_dftw_dfth<<<32, 512, 0, stream>>>(Xin, G, twfg, twbfg);
            k_mix_idfth<<<32, 256, 0, stream>>>(G, w1 + (size_t)l * 524288,
                                                w2 + (size_t)l * 524288, ST, twbfg);
            k_invw_conv<<<256, 256, 0, stream>>>(ST, Xin, conv_w + (size_t)l * 1024,
                                                 conv_b + (size_t)l * 32, skip, Yout,
                                                 twg);
        };
        for (int b = 0; b < 8; ++b) {
            k_lift<<<256, 256, 0, stream>>>(x + (size_t)b * HW_ * 10, fc0_w, fc0_b, A0);
            layer(0, A0, A2, nullptr);   // A2 = h0
            layer(1, A0, A1, nullptr);
            layer(2, A1, A0, A2);        // +h0
            layer(3, A0, A2, nullptr);   // A2 = h1
            layer(4, A0, A1, nullptr);
            layer(5, A1, A0, A2);        // +h1
            // ST dead after layer 5's invw -> stage W1 packs there.
            k_w1prep<<<8, 256, 0, stream>>>(fc1_w, (uint2*)ST);
            k_mlp<<<1024, 256, 0, stream>>>(A0, (const uint2*)ST, fc1_b, fc2_w,
                                            fc2_b, out + (size_t)b * 327680, 1024);
        }
    } else {
        k_probe<<<1, 64, 0, stream>>>(out, (float)(ws_size >> 10));
    }
}